// Round 1
// baseline (1471.312 us; speedup 1.0000x reference)
//
#include <hip/hip_runtime.h>
#include <hip/hip_bf16.h>
#include <hip/hip_cooperative_groups.h>
#include <math.h>

namespace cg = cooperative_groups;

typedef __bf16 bf16_t;
typedef bf16_t bf16x8 __attribute__((ext_vector_type(8)));
typedef float f32x4 __attribute__((ext_vector_type(4)));
typedef unsigned u32x2 __attribute__((ext_vector_type(2)));

#define T_SEQ 128
#define NB 32
#define NV 32000
#define NE 512
#define NH 1024
#define G4 4096          // 4*NH
#define MROWS 4064       // 127*32
#define MPAD 4096

#define NBLK 256

// async global->LDS, 16B per lane, wave-uniform LDS base
__device__ __forceinline__ void g2lds16(const bf16_t* g, bf16_t* l) {
  __builtin_amdgcn_global_load_lds((const __attribute__((address_space(1))) void*)g,
                                   (__attribute__((address_space(3))) void*)l, 16, 0, 0);
}

__device__ __forceinline__ unsigned short bf16bits(float x) {
  bf16_t b = (bf16_t)x;
  return __builtin_bit_cast(unsigned short, b);
}

// ---------------- prep: casts, gather, zeroing ----------------
__global__ void k_prep(const int* __restrict__ idx, const float* __restrict__ emb,
                       const float* __restrict__ W_ih, const float* __restrict__ W_hh,
                       const float* __restrict__ b_ih, const float* __restrict__ b_hh,
                       const float* __restrict__ W_out, const float* __restrict__ h0,
                       bf16_t* __restrict__ W_ih_bf, bf16_t* __restrict__ W_hh_bf,
                       bf16_t* __restrict__ W_out_bf, bf16_t* __restrict__ x_bf,
                       bf16_t* __restrict__ h_all, bf16_t* __restrict__ h0_bf,
                       float* __restrict__ bc, float* __restrict__ rowS,
                       int* __restrict__ tgt, unsigned* __restrict__ bar) {
  const long nW_ih = 4096L * 512;
  const long nW_hh = 4096L * 1024;
  const long nW_out = 32000L * 1024;
  const long nX = 4096L * 512;
  const long nH0 = 32L * 1024;
  const long nHpad = 32L * 1024;
  const long NTOTAL = nW_ih + nW_hh + nW_out + nX + nH0 + nHpad + 3 * 4096L + 1024;
  long stride = (long)gridDim.x * blockDim.x;
  for (long i = (long)blockIdx.x * blockDim.x + threadIdx.x; i < NTOTAL; i += stride) {
    long j = i;
    if (j < nW_ih) { W_ih_bf[j] = (bf16_t)W_ih[j]; continue; }
    j -= nW_ih;
    if (j < nW_hh) { W_hh_bf[j] = (bf16_t)W_hh[j]; continue; }
    j -= nW_hh;
    if (j < nW_out) { W_out_bf[j] = (bf16_t)W_out[j]; continue; }
    j -= nW_out;
    if (j < nX) {
      long m = j >> 9; int e = (int)(j & 511);
      float x = 0.f;
      if (m < MROWS) { x = emb[(long)idx[m] * NE + e]; x = x > 0.f ? x : 0.f; }
      x_bf[j] = (bf16_t)x; continue;
    }
    j -= nX;
    if (j < nH0) { h0_bf[j] = (bf16_t)h0[j]; continue; }
    j -= nH0;
    if (j < nHpad) { h_all[4161536L + j] = (bf16_t)0.f; continue; }  // pad rows 4064..4095
    j -= nHpad;
    if (j < 4096) { bc[j] = b_ih[j] + b_hh[j]; continue; }
    j -= 4096;
    if (j < 4096) { rowS[j] = 0.f; continue; }
    j -= 4096;
    if (j < 4096) { tgt[j] = (j < MROWS) ? idx[j + NB] : 0; continue; }
    j -= 4096;
    { bar[j] = 0u; continue; }
  }
}

// ---------------- GEMM1: gates_x = x @ W_ih^T + (b_ih+b_hh), bf16 out ----------------
__global__ __launch_bounds__(256) void k_gemm1(const bf16_t* __restrict__ A,
                                               const bf16_t* __restrict__ B,
                                               const float* __restrict__ bc,
                                               bf16_t* __restrict__ C) {
  const int K = 512;
  int tid = threadIdx.x, wid = tid >> 6, lane = tid & 63;
  int wm = wid & 1, wn = wid >> 1;
  int quad = lane >> 4, l15 = lane & 15;
  int mBase = blockIdx.x * 64, nBase = blockIdx.y * 128;

  const bf16x8* pa0 = (const bf16x8*)(A + (long)(mBase + wm * 32 + l15) * K + quad * 8);
  const bf16x8* pa1 = (const bf16x8*)(A + (long)(mBase + wm * 32 + 16 + l15) * K + quad * 8);
  const bf16x8* pb[4];
#pragma unroll
  for (int j = 0; j < 4; ++j)
    pb[j] = (const bf16x8*)(B + (long)(nBase + wn * 64 + j * 16 + l15) * K + quad * 8);

  f32x4 acc[2][4];
#pragma unroll
  for (int mi = 0; mi < 2; ++mi)
#pragma unroll
    for (int ni = 0; ni < 4; ++ni) acc[mi][ni] = (f32x4){0.f, 0.f, 0.f, 0.f};

  for (int kk = 0; kk < K / 32; ++kk) {
    bf16x8 a0 = pa0[kk * 4], a1 = pa1[kk * 4];
    bf16x8 b0 = pb[0][kk * 4], b1 = pb[1][kk * 4], b2 = pb[2][kk * 4], b3 = pb[3][kk * 4];
    acc[0][0] = __builtin_amdgcn_mfma_f32_16x16x32_bf16(a0, b0, acc[0][0], 0, 0, 0);
    acc[0][1] = __builtin_amdgcn_mfma_f32_16x16x32_bf16(a0, b1, acc[0][1], 0, 0, 0);
    acc[0][2] = __builtin_amdgcn_mfma_f32_16x16x32_bf16(a0, b2, acc[0][2], 0, 0, 0);
    acc[0][3] = __builtin_amdgcn_mfma_f32_16x16x32_bf16(a0, b3, acc[0][3], 0, 0, 0);
    acc[1][0] = __builtin_amdgcn_mfma_f32_16x16x32_bf16(a1, b0, acc[1][0], 0, 0, 0);
    acc[1][1] = __builtin_amdgcn_mfma_f32_16x16x32_bf16(a1, b1, acc[1][1], 0, 0, 0);
    acc[1][2] = __builtin_amdgcn_mfma_f32_16x16x32_bf16(a1, b2, acc[1][2], 0, 0, 0);
    acc[1][3] = __builtin_amdgcn_mfma_f32_16x16x32_bf16(a1, b3, acc[1][3], 0, 0, 0);
  }
#pragma unroll
  for (int ni = 0; ni < 4; ++ni) {
    int col = nBase + wn * 64 + ni * 16 + l15;
    float bcv = bc[col];
#pragma unroll
    for (int mi = 0; mi < 2; ++mi)
#pragma unroll
      for (int r = 0; r < 4; ++r) {
        int row = mBase + wm * 32 + mi * 16 + quad * 4 + r;
        C[(long)row * G4 + col] = (bf16_t)(acc[mi][ni][r] + bcv);
      }
  }
}

// ---------------- LSTM recurrence v5: per-producer flag dataflow ----------------
// 256 blocks x 512 threads; block = (8 units) x (batch half of 16).
// The 3-stage atomic tree barrier of v4 is replaced by 128 per-producer flags
// per batch half. Producer wave: h stores (agent wt, sc0 sc1) -> vmcnt(0) ack ->
// single flag store. Consumer: ONE poller wave per block spins on a coherent
// dwordx2 load of all 128 flags (512B/wave/round), then __syncthreads releases
// the block. h data loads stay plain (first touch is post-flag => fresh from
// LLC, L2-cacheable for the all-to-all broadcast) — same visibility argument
// as v4's post-barrier loads. flag>=t+1 also implies wave0 finished its red[]
// reads, so one of v4's two per-step __syncthreads stays sufficient.
__global__ __launch_bounds__(512) void k_rec5(const bf16_t* __restrict__ gates_x,
                                              const bf16_t* __restrict__ W_hh_bf,
                                              const bf16_t* __restrict__ h0_bf,
                                              bf16_t* __restrict__ h_all,
                                              const float* __restrict__ c0,
                                              unsigned* __restrict__ flags) {
  __shared__ float red[2 * 16 * 16 * 4];  // [cg][b(16)][col(16)][kh(4)] f32

  int bid = blockIdx.x;
  int mi = bid & 1;              // batch half
  int hb = bid >> 1;             // 0..127 within half
  int gbase = hb * 8;            // first hidden unit owned by this block
  int tid = threadIdx.x, wid = tid >> 6, lane = tid & 63;
  int cg = wid & 1, kh = wid >> 1;
  int quad = lane >> 4, l15 = lane & 15;

  int wrow = (cg ? 2048 : 0) + ((l15 & 8) ? 1024 : 0) + gbase + (l15 & 7);
  const bf16x8* pw = (const bf16x8*)(W_hh_bf + (long)wrow * NH + kh * 256 + quad * 8);
  bf16x8 wfrag[8];
#pragma unroll
  for (int kk = 0; kk < 8; ++kk) wfrag[kk] = pw[kk * 4];  // resident in VGPRs

  // pointwise: threads 0..63 (wave 0): b = tid>>2, unit pair = (tid&3)*2
  int pb = tid >> 2, pu2 = (tid & 3) * 2;
  int u0 = gbase + pu2;
  int bglob = mi * 16 + pb;
  float cst0 = 0.f, cst1 = 0.f;
  if (tid < 64) {
    cst0 = c0[(long)bglob * NH + u0];
    cst1 = c0[(long)bglob * NH + u0 + 1];
  }
  unsigned* h32 = (unsigned*)h_all;
  // poller-wave flag pointer: lane covers flags[mi*128 + 2*lane .. +1]
  const unsigned* fp = flags + mi * 128 + (lane << 1);

  for (int t = 0; t < T_SEQ - 1; ++t) {
    // prefetch gates_x pairs (independent of h_prev; overlaps flag wait)
    unsigned gxi2 = 0, gxf2 = 0, gxg2 = 0, gxo2 = 0;
    if (tid < 64) {
      const unsigned* gp = (const unsigned*)(gates_x + (long)(t * NB + bglob) * G4);
      int q = u0 >> 1;
      gxi2 = gp[q]; gxf2 = gp[512 + q]; gxg2 = gp[1024 + q]; gxo2 = gp[1536 + q];
    }

    // wave 0 polls its half's 128 producer flags until all >= t
    if (t > 0 && wid == 0) {
      u32x2 fv;
      while (1) {
        asm volatile("global_load_dwordx2 %0, %1, off sc0 sc1\n\t"
                     "s_waitcnt vmcnt(0)"
                     : "=&v"(fv) : "v"(fp) : "memory");
        int ok = (fv.x >= (unsigned)t) & (fv.y >= (unsigned)t);
        if (__all(ok)) break;
      }
    }
    __syncthreads();  // release block once h[t-1] visible; also: prev red consumed

    const bf16_t* hp = (t == 0) ? h0_bf : (h_all + (long)(t - 1) * NB * NH);
    const bf16x8* pa = (const bf16x8*)(hp + (long)(mi * 16 + l15) * NH + kh * 256 + quad * 8);
    bf16x8 hfr[8];
#pragma unroll
    for (int kk = 0; kk < 8; ++kk) hfr[kk] = pa[kk * 4];
    // split 8-deep dependent MFMA chain into 2x4
    f32x4 acc0 = (f32x4){0.f, 0.f, 0.f, 0.f};
    f32x4 acc1 = (f32x4){0.f, 0.f, 0.f, 0.f};
#pragma unroll
    for (int kk = 0; kk < 4; ++kk) {
      acc0 = __builtin_amdgcn_mfma_f32_16x16x32_bf16(hfr[kk], wfrag[kk], acc0, 0, 0, 0);
      acc1 = __builtin_amdgcn_mfma_f32_16x16x32_bf16(hfr[kk + 4], wfrag[kk + 4], acc1, 0, 0, 0);
    }
    f32x4 acc = acc0 + acc1;
#pragma unroll
    for (int r = 0; r < 4; ++r) {
      int b = quad * 4 + r;
      red[(((cg << 4) + b) << 6) + (l15 << 2) + kh] = acc[r];
    }
    __syncthreads();

    if (tid < 64) {
      const float4* rp = (const float4*)red;
      // two adjacent units d=0,1
      float hv[2];
#pragma unroll
      for (int d = 0; d < 2; ++d) {
        int q = pu2 + d;
        float4 vi = rp[(pb << 4) + q];
        float4 vf = rp[(pb << 4) + 8 + q];
        float4 vg = rp[((16 + pb) << 4) + q];
        float4 vo = rp[((16 + pb) << 4) + 8 + q];
        unsigned bi = d ? (gxi2 & 0xffff0000u) : (gxi2 << 16);
        unsigned bff = d ? (gxf2 & 0xffff0000u) : (gxf2 << 16);
        unsigned bg = d ? (gxg2 & 0xffff0000u) : (gxg2 << 16);
        unsigned bo = d ? (gxo2 & 0xffff0000u) : (gxo2 << 16);
        float iv = vi.x + vi.y + vi.z + vi.w + __builtin_bit_cast(float, bi);
        float fv = vf.x + vf.y + vf.z + vf.w + __builtin_bit_cast(float, bff);
        float gv = vg.x + vg.y + vg.z + vg.w + __builtin_bit_cast(float, bg);
        float ov = vo.x + vo.y + vo.z + vo.w + __builtin_bit_cast(float, bo);
        float si = 1.f / (1.f + __expf(-iv));
        float sf = 1.f / (1.f + __expf(-fv));
        float so = 1.f / (1.f + __expf(-ov));
        float tg = 1.f - 2.f / (__expf(2.f * gv) + 1.f);
        float& cs = d ? cst1 : cst0;
        cs = sf * cs + si * tg;
        float th = 1.f - 2.f / (__expf(2.f * cs) + 1.f);
        hv[d] = so * th;
      }
      unsigned pack = (unsigned)bf16bits(hv[0]) | ((unsigned)bf16bits(hv[1]) << 16);
      // agent-scope write-through store: visible at LLC, no L2 dirty line
      __hip_atomic_store(&h32[(long)(t * NB + bglob) * 512 + (u0 >> 1)], pack,
                         __ATOMIC_RELAXED, __HIP_MEMORY_SCOPE_AGENT);
      asm volatile("" ::: "memory");
      __builtin_amdgcn_s_waitcnt(0x0f70);  // vmcnt(0): h stores acked at LLC
      asm volatile("" ::: "memory");
      if (tid == 0)
        __hip_atomic_store(&flags[mi * 128 + hb], (unsigned)(t + 1),
                           __ATOMIC_RELAXED, __HIP_MEMORY_SCOPE_AGENT);
    }
  }
}

// ---------------- GEMM2 v2: m97-style LDS-staged, exp-rowsum epilogue ----------------
__global__ __launch_bounds__(256) void k_gemm2(const bf16_t* __restrict__ A,
                                               const bf16_t* __restrict__ B,
                                               const float* __restrict__ b_out,
                                               float* __restrict__ rowS) {
  __shared__ bf16_t As[128 * 32];
  __shared__ bf16_t Bs[128 * 32];
  const int K = 1024;
  int tid = threadIdx.x, wid = tid >> 6, lane = tid & 63;
  int wm = wid & 1, wn = wid >> 1;
  int quad = lane >> 4, l15 = lane & 15;
  int mBase = blockIdx.x * 128, nBase = blockIdx.y * 128;

  int rc = lane >> 2, seg = lane & 3;
  int cA0 = 2 * wid, cA1 = 2 * wid + 1;
  const bf16_t* gA0 = A + (size_t)(mBase + cA0 * 16 + rc) * K + seg * 8;
  const bf16_t* gA1 = A + (size_t)(mBase + cA1 * 16 + rc) * K + seg * 8;
  const bf16_t* gB0 = B + (size_t)(nBase + cA0 * 16 + rc) * K + seg * 8;
  const bf16_t* gB1 = B + (size_t)(nBase + cA1 * 16 + rc) * K + seg * 8;
  bf16_t* lA0 = As + cA0 * 512;
  bf16_t* lA1 = As + cA1 * 512;
  bf16_t* lB0 = Bs + cA0 * 512;
  bf16_t* lB1 = Bs + cA1 * 512;

  const bf16x8* pa[4];
  const bf16x8* pbf[4];
#pragma unroll
  for (int i = 0; i < 4; ++i) {
    pa[i] = (const bf16x8*)(As + (wm * 64 + i * 16 + l15) * 32 + quad * 8);
    pbf[i] = (const bf16x8*)(Bs + (wn * 64 + i * 16 + l15) * 32 + quad * 8);
  }

  f32x4 acc[4][4];
#pragma unroll
  for (int i = 0; i < 4; ++i)
#pragma unroll
    for (int j = 0; j < 4; ++j) acc[i][j] = (f32x4){0.f, 0.f, 0.f, 0.f};

  for (int kt = 0; kt < K / 32; ++kt) {
    g2lds16(gA0 + kt * 32, lA0);
    g2lds16(gA1 + kt * 32, lA1);
    g2lds16(gB0 + kt * 32, lB0);
    g2lds16(gB1 + kt * 32, lB1);
    __syncthreads();

    bf16x8 af[4], bf[4];
#pragma unroll
    for (int i = 0; i < 4; ++i) { af[i] = *pa[i]; bf[i] = *pbf[i]; }
#pragma unroll
    for (int i = 0; i < 4; ++i)
#pragma unroll
      for (int j = 0; j < 4; ++j)
        acc[i][j] = __builtin_amdgcn_mfma_f32_16x16x32_bf16(af[i], bf[j], acc[i][j], 0, 0, 0);
    __syncthreads();
  }

#pragma unroll
  for (int i = 0; i < 4; ++i) {
    float rs[4] = {0.f, 0.f, 0.f, 0.f};
#pragma unroll
    for (int j = 0; j < 4; ++j) {
      int col = nBase + wn * 64 + j * 16 + l15;
      float bb = b_out[col];
#pragma unroll
      for (int r = 0; r < 4; ++r) rs[r] += __expf(acc[i][j][r] + bb);
    }
#pragma unroll
    for (int r = 0; r < 4; ++r) {
#pragma unroll
      for (int s = 1; s < 16; s <<= 1) rs[r] += __shfl_xor(rs[r], s);
      if (l15 == 0) {
        int row = mBase + wm * 64 + i * 16 + quad * 4 + r;
        if (row < MROWS) atomicAdd(&rowS[row], rs[r]);
      }
    }
  }
}

// ---------------- target logits ----------------
__global__ __launch_bounds__(256) void k_tgt(const bf16_t* __restrict__ h_all,
                                             const bf16_t* __restrict__ W_out_bf,
                                             const float* __restrict__ b_out,
                                             const int* __restrict__ tgt,
                                             float* __restrict__ tgt_logit) {
  int gw = (int)((blockIdx.x * blockDim.x + threadIdx.x) >> 6);
  int lane = threadIdx.x & 63;
  if (gw >= MROWS) return;
  int v = tgt[gw];
  const bf16x8* ph = (const bf16x8*)(h_all + (long)gw * NH + lane * 16);
  const bf16x8* pw = (const bf16x8*)(W_out_bf + (long)v * NH + lane * 16);
  float acc = 0.f;
#pragma unroll
  for (int j = 0; j < 2; ++j) {
    bf16x8 h8 = ph[j], w8 = pw[j];
#pragma unroll
    for (int q = 0; q < 8; ++q) acc += (float)h8[q] * (float)w8[q];
  }
#pragma unroll
  for (int s = 1; s < 64; s <<= 1) acc += __shfl_xor(acc, s);
  if (lane == 0) tgt_logit[gw] = acc + b_out[v];
}

// ---------------- final loss reduction ----------------
__global__ __launch_bounds__(256) void k_loss(const float* __restrict__ rowS,
                                              const float* __restrict__ tl,
                                              const int* __restrict__ tgt,
                                              float* __restrict__ out) {
  __shared__ float sm[256];
  float s = 0.f;
  for (int i = threadIdx.x; i < MROWS; i += 256)
    if (tgt[i] != 0) s += logf(rowS[i]) - tl[i];
  sm[threadIdx.x] = s;
  __syncthreads();
  for (int off = 128; off > 0; off >>= 1) {
    if (threadIdx.x < off) sm[threadIdx.x] += sm[threadIdx.x + off];
    __syncthreads();
  }
  if (threadIdx.x == 0) out[0] = sm[0];
}

extern "C" void kernel_launch(void* const* d_in, const int* in_sizes, int n_in,
                              void* d_out, int out_size, void* d_ws, size_t ws_size,
                              hipStream_t stream) {
  const int* idx = (const int*)d_in[0];
  const float* emb = (const float*)d_in[1];
  const float* W_ih = (const float*)d_in[2];
  const float* W_hh = (const float*)d_in[3];
  const float* b_ih = (const float*)d_in[4];
  const float* b_hh = (const float*)d_in[5];
  const float* W_out = (const float*)d_in[6];
  const float* b_out = (const float*)d_in[7];
  const float* h0 = (const float*)d_in[8];
  const float* c0 = (const float*)d_in[9];

  char* ws = (char*)d_ws;
  bf16_t* W_ih_bf = (bf16_t*)ws;            ws += 4096L * 512 * 2;
  bf16_t* W_hh_bf = (bf16_t*)ws;            ws += 4096L * 1024 * 2;
  bf16_t* W_out_bf = (bf16_t*)ws;           ws += 32000L * 1024 * 2;
  bf16_t* x_bf = (bf16_t*)ws;               ws += 4096L * 512 * 2;
  bf16_t* gates_x = (bf16_t*)ws;            ws += 4096L * 4096 * 2;
  bf16_t* h_all = (bf16_t*)ws;              ws += 4096L * 1024 * 2;
  bf16_t* h0_bf = (bf16_t*)ws;              ws += 32L * 1024 * 2;
  float* bc = (float*)ws;                   ws += 4096L * 4;
  float* rowS = (float*)ws;                 ws += 4096L * 4;
  float* tgt_logit = (float*)ws;            ws += 4096L * 4;
  int* tgt = (int*)ws;                      ws += 4096L * 4;
  unsigned* bar = (unsigned*)ws;            ws += 1024L * 4;

  k_prep<<<4096, 256, 0, stream>>>(idx, emb, W_ih, W_hh, b_ih, b_hh, W_out, h0,
                                   W_ih_bf, W_hh_bf, W_out_bf, x_bf, h_all, h0_bf,
                                   bc, rowS, tgt, bar);

  k_gemm1<<<dim3(64, 32), 256, 0, stream>>>(x_bf, W_ih_bf, bc, gates_x);

  {
    void* args[] = {(void*)&gates_x, (void*)&W_hh_bf, (void*)&h0_bf, (void*)&h_all,
                    (void*)&c0, (void*)&bar};
    hipLaunchCooperativeKernel((void*)k_rec5, dim3(NBLK), dim3(512), args, 0, stream);
  }

  k_gemm2<<<dim3(32, 250), 256, 0, stream>>>(h_all, W_out_bf, b_out, rowS);

  k_tgt<<<1016, 256, 0, stream>>>(h_all, W_out_bf, b_out, tgt, tgt_logit);

  k_loss<<<1, 256, 0, stream>>>(rowS, tgt_logit, tgt, (float*)d_out);
}

// Round 2
// 1468.256 us; speedup vs baseline: 1.0021x; 1.0021x over previous
//
#include <hip/hip_runtime.h>
#include <hip/hip_bf16.h>
#include <hip/hip_cooperative_groups.h>
#include <math.h>

namespace cg = cooperative_groups;

typedef __bf16 bf16_t;
typedef bf16_t bf16x8 __attribute__((ext_vector_type(8)));
typedef float f32x4 __attribute__((ext_vector_type(4)));

#define T_SEQ 128
#define NB 32
#define NV 32000
#define NE 512
#define NH 1024
#define G4 4096          // 4*NH
#define MROWS 4064       // 127*32
#define MPAD 4096

#define NBLK 256

// async global->LDS, 16B per lane, wave-uniform LDS base
__device__ __forceinline__ void g2lds16(const bf16_t* g, bf16_t* l) {
  __builtin_amdgcn_global_load_lds((const __attribute__((address_space(1))) void*)g,
                                   (__attribute__((address_space(3))) void*)l, 16, 0, 0);
}

__device__ __forceinline__ unsigned short bf16bits(float x) {
  bf16_t b = (bf16_t)x;
  return __builtin_bit_cast(unsigned short, b);
}

// ---------------- prep: casts, gather, zeroing ----------------
__global__ void k_prep(const int* __restrict__ idx, const float* __restrict__ emb,
                       const float* __restrict__ W_ih, const float* __restrict__ W_hh,
                       const float* __restrict__ b_ih, const float* __restrict__ b_hh,
                       const float* __restrict__ W_out, const float* __restrict__ h0,
                       bf16_t* __restrict__ W_ih_bf, bf16_t* __restrict__ W_hh_bf,
                       bf16_t* __restrict__ W_out_bf, bf16_t* __restrict__ x_bf,
                       bf16_t* __restrict__ h_all, bf16_t* __restrict__ h0_bf,
                       float* __restrict__ bc, float* __restrict__ rowS,
                       int* __restrict__ tgt, unsigned* __restrict__ bar) {
  const long nW_ih = 4096L * 512;
  const long nW_hh = 4096L * 1024;
  const long nW_out = 32000L * 1024;
  const long nX = 4096L * 512;
  const long nH0 = 32L * 1024;
  const long nHpad = 32L * 1024;
  const long NTOTAL = nW_ih + nW_hh + nW_out + nX + nH0 + nHpad + 3 * 4096L + 1024;
  long stride = (long)gridDim.x * blockDim.x;
  for (long i = (long)blockIdx.x * blockDim.x + threadIdx.x; i < NTOTAL; i += stride) {
    long j = i;
    if (j < nW_ih) { W_ih_bf[j] = (bf16_t)W_ih[j]; continue; }
    j -= nW_ih;
    if (j < nW_hh) { W_hh_bf[j] = (bf16_t)W_hh[j]; continue; }
    j -= nW_hh;
    if (j < nW_out) { W_out_bf[j] = (bf16_t)W_out[j]; continue; }
    j -= nW_out;
    if (j < nX) {
      long m = j >> 9; int e = (int)(j & 511);
      float x = 0.f;
      if (m < MROWS) { x = emb[(long)idx[m] * NE + e]; x = x > 0.f ? x : 0.f; }
      x_bf[j] = (bf16_t)x; continue;
    }
    j -= nX;
    if (j < nH0) { h0_bf[j] = (bf16_t)h0[j]; continue; }
    j -= nH0;
    if (j < nHpad) { h_all[4161536L + j] = (bf16_t)0.f; continue; }  // pad rows 4064..4095
    j -= nHpad;
    if (j < 4096) { bc[j] = b_ih[j] + b_hh[j]; continue; }
    j -= 4096;
    if (j < 4096) { rowS[j] = 0.f; continue; }
    j -= 4096;
    if (j < 4096) { tgt[j] = (j < MROWS) ? idx[j + NB] : 0; continue; }
    j -= 4096;
    { bar[j] = 0u; continue; }
  }
}

// ---------------- GEMM1: gates_x = x @ W_ih^T + (b_ih+b_hh), bf16 out ----------------
__global__ __launch_bounds__(256) void k_gemm1(const bf16_t* __restrict__ A,
                                               const bf16_t* __restrict__ B,
                                               const float* __restrict__ bc,
                                               bf16_t* __restrict__ C) {
  const int K = 512;
  int tid = threadIdx.x, wid = tid >> 6, lane = tid & 63;
  int wm = wid & 1, wn = wid >> 1;
  int quad = lane >> 4, l15 = lane & 15;
  int mBase = blockIdx.x * 64, nBase = blockIdx.y * 128;

  const bf16x8* pa0 = (const bf16x8*)(A + (long)(mBase + wm * 32 + l15) * K + quad * 8);
  const bf16x8* pa1 = (const bf16x8*)(A + (long)(mBase + wm * 32 + 16 + l15) * K + quad * 8);
  const bf16x8* pb[4];
#pragma unroll
  for (int j = 0; j < 4; ++j)
    pb[j] = (const bf16x8*)(B + (long)(nBase + wn * 64 + j * 16 + l15) * K + quad * 8);

  f32x4 acc[2][4];
#pragma unroll
  for (int mi = 0; mi < 2; ++mi)
#pragma unroll
    for (int ni = 0; ni < 4; ++ni) acc[mi][ni] = (f32x4){0.f, 0.f, 0.f, 0.f};

  for (int kk = 0; kk < K / 32; ++kk) {
    bf16x8 a0 = pa0[kk * 4], a1 = pa1[kk * 4];
    bf16x8 b0 = pb[0][kk * 4], b1 = pb[1][kk * 4], b2 = pb[2][kk * 4], b3 = pb[3][kk * 4];
    acc[0][0] = __builtin_amdgcn_mfma_f32_16x16x32_bf16(a0, b0, acc[0][0], 0, 0, 0);
    acc[0][1] = __builtin_amdgcn_mfma_f32_16x16x32_bf16(a0, b1, acc[0][1], 0, 0, 0);
    acc[0][2] = __builtin_amdgcn_mfma_f32_16x16x32_bf16(a0, b2, acc[0][2], 0, 0, 0);
    acc[0][3] = __builtin_amdgcn_mfma_f32_16x16x32_bf16(a0, b3, acc[0][3], 0, 0, 0);
    acc[1][0] = __builtin_amdgcn_mfma_f32_16x16x32_bf16(a1, b0, acc[1][0], 0, 0, 0);
    acc[1][1] = __builtin_amdgcn_mfma_f32_16x16x32_bf16(a1, b1, acc[1][1], 0, 0, 0);
    acc[1][2] = __builtin_amdgcn_mfma_f32_16x16x32_bf16(a1, b2, acc[1][2], 0, 0, 0);
    acc[1][3] = __builtin_amdgcn_mfma_f32_16x16x32_bf16(a1, b3, acc[1][3], 0, 0, 0);
  }
#pragma unroll
  for (int ni = 0; ni < 4; ++ni) {
    int col = nBase + wn * 64 + ni * 16 + l15;
    float bcv = bc[col];
#pragma unroll
    for (int mi = 0; mi < 2; ++mi)
#pragma unroll
      for (int r = 0; r < 4; ++r) {
        int row = mBase + wm * 32 + mi * 16 + quad * 4 + r;
        C[(long)row * G4 + col] = (bf16_t)(acc[mi][ni][r] + bcv);
      }
  }
}

// ---------------- LSTM recurrence v6: flat group cells + per-wave gating ----------------
// 256 blocks x 512 threads; block = (8 units) x (batch half of 16).
// vs v4 (proven 602us): (1) barrier flattened — producers fetch_add a CONTIGUOUS
// group cell (16 blocks/cell, 8 cells/half); consumer wave kh polls ONLY cells
// 2kh,2kh+1 (its h columns [256kh,256kh+256) come exactly from those producer
// groups) with lanes 0-1, s_sleep-paced (v4's low-traffic poll pattern; v5's
// 64-lane sc0sc1 storm was the regression). Removes root+gen RTTs and decouples
// waves from stragglers they don't consume. (2) red[] double-buffered -> one
// __syncthreads/step (anti-dep covered transitively: red[t&1] overwrite at t+2
// requires a producer signal at t+1, which required polling OUR cell >=16(t+1),
// which required our wave0 past its red(t) reads). (3) red stride 64->68 floats:
// float4 read goes 16-way-conflict -> uniform (b128 floor); write 8-way -> 4-way.
// (4) revert to v4's single MFMA chain (first MFMA gates on first load only).
__global__ __launch_bounds__(512) void k_rec6(const bf16_t* __restrict__ gates_x,
                                              const bf16_t* __restrict__ W_hh_bf,
                                              const bf16_t* __restrict__ h0_bf,
                                              bf16_t* __restrict__ h_all,
                                              const float* __restrict__ c0,
                                              unsigned* __restrict__ bar) {
  __shared__ __align__(16) float red[2][32 * 68];  // dbuf, row stride 68 (pad 4)

  int bid = blockIdx.x;
  int mi = bid & 1;              // batch half
  int hb = bid >> 1;             // 0..127 within half
  int gbase = hb * 8;            // first hidden unit owned by this block
  int tid = threadIdx.x, wid = tid >> 6, lane = tid & 63;
  int cg = wid & 1, kh = wid >> 1;
  int quad = lane >> 4, l15 = lane & 15;

  int wrow = (cg ? 2048 : 0) + ((l15 & 8) ? 1024 : 0) + gbase + (l15 & 7);
  const bf16x8* pw = (const bf16x8*)(W_hh_bf + (long)wrow * NH + kh * 256 + quad * 8);
  bf16x8 wfrag[8];
#pragma unroll
  for (int kk = 0; kk < 8; ++kk) wfrag[kk] = pw[kk * 4];  // resident in VGPRs

  // consumer cells for this wave (groups 2kh, 2kh+1; 128B-separated lines)
  unsigned* cellp = bar + mi * 512 + (2 * kh + (lane & 1)) * 32;
  // producer cell for this block (contiguous grouping: units [g*128,(g+1)*128))
  unsigned* mycell = bar + mi * 512 + (hb >> 4) * 32;

  // pointwise: threads 0..63 (wave 0): b = tid>>2, unit pair = (tid&3)*2
  int pb = tid >> 2, pu2 = (tid & 3) * 2;
  int u0 = gbase + pu2;
  int bglob = mi * 16 + pb;
  float cst0 = 0.f, cst1 = 0.f;
  if (tid < 64) {
    cst0 = c0[(long)bglob * NH + u0];
    cst1 = c0[(long)bglob * NH + u0 + 1];
  }
  unsigned* h32 = (unsigned*)h_all;

  for (int t = 0; t < T_SEQ - 1; ++t) {
    // prefetch gates_x pairs (independent of h_prev; overlaps poll wait)
    unsigned gxi2 = 0, gxf2 = 0, gxg2 = 0, gxo2 = 0;
    if (tid < 64) {
      const unsigned* gp = (const unsigned*)(gates_x + (long)(t * NB + bglob) * G4);
      int q = u0 >> 1;
      gxi2 = gp[q]; gxf2 = gp[512 + q]; gxg2 = gp[1024 + q]; gxo2 = gp[1536 + q];
    }

    // per-wave gate: wait for the 2 producer groups this wave consumes
    if (t > 0 && lane < 2) {
      unsigned need = 16u * (unsigned)t;
      while (__hip_atomic_load(cellp, __ATOMIC_RELAXED, __HIP_MEMORY_SCOPE_AGENT) < need)
        __builtin_amdgcn_s_sleep(1);
    }
    asm volatile("" ::: "memory");  // no hoisting h loads above the poll

    const bf16_t* hp = (t == 0) ? h0_bf : (h_all + (long)(t - 1) * NB * NH);
    const bf16x8* pa = (const bf16x8*)(hp + (long)(mi * 16 + l15) * NH + kh * 256 + quad * 8);
    f32x4 acc = (f32x4){0.f, 0.f, 0.f, 0.f};
#pragma unroll
    for (int kk = 0; kk < 8; ++kk) {
      bf16x8 a = pa[kk * 4];
      acc = __builtin_amdgcn_mfma_f32_16x16x32_bf16(a, wfrag[kk], acc, 0, 0, 0);
    }
    float* rb = red[t & 1];
#pragma unroll
    for (int r = 0; r < 4; ++r) {
      int row = (cg << 4) + (quad << 2) + r;
      rb[row * 68 + (l15 << 2) + kh] = acc[r];
    }
    __syncthreads();

    if (tid < 64) {
      const float* rc = red[t & 1];
      float hv[2];
#pragma unroll
      for (int d = 0; d < 2; ++d) {
        int q = pu2 + d;
        float4 vi = *(const float4*)(rc + pb * 68 + (q << 2));
        float4 vf = *(const float4*)(rc + pb * 68 + ((8 + q) << 2));
        float4 vg = *(const float4*)(rc + (16 + pb) * 68 + (q << 2));
        float4 vo = *(const float4*)(rc + (16 + pb) * 68 + ((8 + q) << 2));
        unsigned bi = d ? (gxi2 & 0xffff0000u) : (gxi2 << 16);
        unsigned bff = d ? (gxf2 & 0xffff0000u) : (gxf2 << 16);
        unsigned bg = d ? (gxg2 & 0xffff0000u) : (gxg2 << 16);
        unsigned bo = d ? (gxo2 & 0xffff0000u) : (gxo2 << 16);
        float iv = vi.x + vi.y + vi.z + vi.w + __builtin_bit_cast(float, bi);
        float fv = vf.x + vf.y + vf.z + vf.w + __builtin_bit_cast(float, bff);
        float gv = vg.x + vg.y + vg.z + vg.w + __builtin_bit_cast(float, bg);
        float ov = vo.x + vo.y + vo.z + vo.w + __builtin_bit_cast(float, bo);
        float si = 1.f / (1.f + __expf(-iv));
        float sf = 1.f / (1.f + __expf(-fv));
        float so = 1.f / (1.f + __expf(-ov));
        float tg = 1.f - 2.f / (__expf(2.f * gv) + 1.f);
        float& cs = d ? cst1 : cst0;
        cs = sf * cs + si * tg;
        float th = 1.f - 2.f / (__expf(2.f * cs) + 1.f);
        hv[d] = so * th;
      }
      unsigned pack = (unsigned)bf16bits(hv[0]) | ((unsigned)bf16bits(hv[1]) << 16);
      // agent-scope write-through store: visible at LLC, no L2 dirty line
      __hip_atomic_store(&h32[(long)(t * NB + bglob) * 512 + (u0 >> 1)], pack,
                         __ATOMIC_RELAXED, __HIP_MEMORY_SCOPE_AGENT);
      if (t < T_SEQ - 2) {
        asm volatile("" ::: "memory");
        __builtin_amdgcn_s_waitcnt(0x0f70);  // vmcnt(0): h stores acked at LLC
        asm volatile("" ::: "memory");
        if (tid == 0)
          __hip_atomic_fetch_add(mycell, 1u, __ATOMIC_RELAXED,
                                 __HIP_MEMORY_SCOPE_AGENT);
      }
    }
  }
}

// ---------------- GEMM2 v2: m97-style LDS-staged, exp-rowsum epilogue ----------------
__global__ __launch_bounds__(256) void k_gemm2(const bf16_t* __restrict__ A,
                                               const bf16_t* __restrict__ B,
                                               const float* __restrict__ b_out,
                                               float* __restrict__ rowS) {
  __shared__ bf16_t As[128 * 32];
  __shared__ bf16_t Bs[128 * 32];
  const int K = 1024;
  int tid = threadIdx.x, wid = tid >> 6, lane = tid & 63;
  int wm = wid & 1, wn = wid >> 1;
  int quad = lane >> 4, l15 = lane & 15;
  int mBase = blockIdx.x * 128, nBase = blockIdx.y * 128;

  int rc = lane >> 2, seg = lane & 3;
  int cA0 = 2 * wid, cA1 = 2 * wid + 1;
  const bf16_t* gA0 = A + (size_t)(mBase + cA0 * 16 + rc) * K + seg * 8;
  const bf16_t* gA1 = A + (size_t)(mBase + cA1 * 16 + rc) * K + seg * 8;
  const bf16_t* gB0 = B + (size_t)(nBase + cA0 * 16 + rc) * K + seg * 8;
  const bf16_t* gB1 = B + (size_t)(nBase + cA1 * 16 + rc) * K + seg * 8;
  bf16_t* lA0 = As + cA0 * 512;
  bf16_t* lA1 = As + cA1 * 512;
  bf16_t* lB0 = Bs + cA0 * 512;
  bf16_t* lB1 = Bs + cA1 * 512;

  const bf16x8* pa[4];
  const bf16x8* pbf[4];
#pragma unroll
  for (int i = 0; i < 4; ++i) {
    pa[i] = (const bf16x8*)(As + (wm * 64 + i * 16 + l15) * 32 + quad * 8);
    pbf[i] = (const bf16x8*)(Bs + (wn * 64 + i * 16 + l15) * 32 + quad * 8);
  }

  f32x4 acc[4][4];
#pragma unroll
  for (int i = 0; i < 4; ++i)
#pragma unroll
    for (int j = 0; j < 4; ++j) acc[i][j] = (f32x4){0.f, 0.f, 0.f, 0.f};

  for (int kt = 0; kt < K / 32; ++kt) {
    g2lds16(gA0 + kt * 32, lA0);
    g2lds16(gA1 + kt * 32, lA1);
    g2lds16(gB0 + kt * 32, lB0);
    g2lds16(gB1 + kt * 32, lB1);
    __syncthreads();

    bf16x8 af[4], bf[4];
#pragma unroll
    for (int i = 0; i < 4; ++i) { af[i] = *pa[i]; bf[i] = *pbf[i]; }
#pragma unroll
    for (int i = 0; i < 4; ++i)
#pragma unroll
      for (int j = 0; j < 4; ++j)
        acc[i][j] = __builtin_amdgcn_mfma_f32_16x16x32_bf16(af[i], bf[j], acc[i][j], 0, 0, 0);
    __syncthreads();
  }

#pragma unroll
  for (int i = 0; i < 4; ++i) {
    float rs[4] = {0.f, 0.f, 0.f, 0.f};
#pragma unroll
    for (int j = 0; j < 4; ++j) {
      int col = nBase + wn * 64 + j * 16 + l15;
      float bb = b_out[col];
#pragma unroll
      for (int r = 0; r < 4; ++r) rs[r] += __expf(acc[i][j][r] + bb);
    }
#pragma unroll
    for (int r = 0; r < 4; ++r) {
#pragma unroll
      for (int s = 1; s < 16; s <<= 1) rs[r] += __shfl_xor(rs[r], s);
      if (l15 == 0) {
        int row = mBase + wm * 64 + i * 16 + quad * 4 + r;
        if (row < MROWS) atomicAdd(&rowS[row], rs[r]);
      }
    }
  }
}

// ---------------- target logits ----------------
__global__ __launch_bounds__(256) void k_tgt(const bf16_t* __restrict__ h_all,
                                             const bf16_t* __restrict__ W_out_bf,
                                             const float* __restrict__ b_out,
                                             const int* __restrict__ tgt,
                                             float* __restrict__ tgt_logit) {
  int gw = (int)((blockIdx.x * blockDim.x + threadIdx.x) >> 6);
  int lane = threadIdx.x & 63;
  if (gw >= MROWS) return;
  int v = tgt[gw];
  const bf16x8* ph = (const bf16x8*)(h_all + (long)gw * NH + lane * 16);
  const bf16x8* pw = (const bf16x8*)(W_out_bf + (long)v * NH + lane * 16);
  float acc = 0.f;
#pragma unroll
  for (int j = 0; j < 2; ++j) {
    bf16x8 h8 = ph[j], w8 = pw[j];
#pragma unroll
    for (int q = 0; q < 8; ++q) acc += (float)h8[q] * (float)w8[q];
  }
#pragma unroll
  for (int s = 1; s < 64; s <<= 1) acc += __shfl_xor(acc, s);
  if (lane == 0) tgt_logit[gw] = acc + b_out[v];
}

// ---------------- final loss reduction ----------------
__global__ __launch_bounds__(256) void k_loss(const float* __restrict__ rowS,
                                              const float* __restrict__ tl,
                                              const int* __restrict__ tgt,
                                              float* __restrict__ out) {
  __shared__ float sm[256];
  float s = 0.f;
  for (int i = threadIdx.x; i < MROWS; i += 256)
    if (tgt[i] != 0) s += logf(rowS[i]) - tl[i];
  sm[threadIdx.x] = s;
  __syncthreads();
  for (int off = 128; off > 0; off >>= 1) {
    if (threadIdx.x < off) sm[threadIdx.x] += sm[threadIdx.x + off];
    __syncthreads();
  }
  if (threadIdx.x == 0) out[0] = sm[0];
}

extern "C" void kernel_launch(void* const* d_in, const int* in_sizes, int n_in,
                              void* d_out, int out_size, void* d_ws, size_t ws_size,
                              hipStream_t stream) {
  const int* idx = (const int*)d_in[0];
  const float* emb = (const float*)d_in[1];
  const float* W_ih = (const float*)d_in[2];
  const float* W_hh = (const float*)d_in[3];
  const float* b_ih = (const float*)d_in[4];
  const float* b_hh = (const float*)d_in[5];
  const float* W_out = (const float*)d_in[6];
  const float* b_out = (const float*)d_in[7];
  const float* h0 = (const float*)d_in[8];
  const float* c0 = (const float*)d_in[9];

  char* ws = (char*)d_ws;
  bf16_t* W_ih_bf = (bf16_t*)ws;            ws += 4096L * 512 * 2;
  bf16_t* W_hh_bf = (bf16_t*)ws;            ws += 4096L * 1024 * 2;
  bf16_t* W_out_bf = (bf16_t*)ws;           ws += 32000L * 1024 * 2;
  bf16_t* x_bf = (bf16_t*)ws;               ws += 4096L * 512 * 2;
  bf16_t* gates_x = (bf16_t*)ws;            ws += 4096L * 4096 * 2;
  bf16_t* h_all = (bf16_t*)ws;              ws += 4096L * 1024 * 2;
  bf16_t* h0_bf = (bf16_t*)ws;              ws += 32L * 1024 * 2;
  float* bc = (float*)ws;                   ws += 4096L * 4;
  float* rowS = (float*)ws;                 ws += 4096L * 4;
  float* tgt_logit = (float*)ws;            ws += 4096L * 4;
  int* tgt = (int*)ws;                      ws += 4096L * 4;
  unsigned* bar = (unsigned*)ws;            ws += 1024L * 4;

  k_prep<<<4096, 256, 0, stream>>>(idx, emb, W_ih, W_hh, b_ih, b_hh, W_out, h0,
                                   W_ih_bf, W_hh_bf, W_out_bf, x_bf, h_all, h0_bf,
                                   bc, rowS, tgt, bar);

  k_gemm1<<<dim3(64, 32), 256, 0, stream>>>(x_bf, W_ih_bf, bc, gates_x);

  {
    void* args[] = {(void*)&gates_x, (void*)&W_hh_bf, (void*)&h0_bf, (void*)&h_all,
                    (void*)&c0, (void*)&bar};
    hipLaunchCooperativeKernel((void*)k_rec6, dim3(NBLK), dim3(512), args, 0, stream);
  }

  k_gemm2<<<dim3(32, 250), 256, 0, stream>>>(h_all, W_out_bf, b_out, rowS);

  k_tgt<<<1016, 256, 0, stream>>>(h_all, W_out_bf, b_out, tgt, tgt_logit);

  k_loss<<<1, 256, 0, stream>>>(rowS, tgt_logit, tgt, (float*)d_out);
}

// Round 4
// 1332.025 us; speedup vs baseline: 1.1046x; 1.1023x over previous
//
#include <hip/hip_runtime.h>
#include <hip/hip_bf16.h>
#include <hip/hip_cooperative_groups.h>
#include <math.h>

namespace cg = cooperative_groups;

typedef __bf16 bf16_t;
typedef bf16_t bf16x8 __attribute__((ext_vector_type(8)));
typedef float f32x4 __attribute__((ext_vector_type(4)));
typedef unsigned u32x2 __attribute__((ext_vector_type(2)));

#define T_SEQ 128
#define NB 32
#define NV 32000
#define NE 512
#define NH 1024
#define G4 4096          // 4*NH
#define MROWS 4064       // 127*32
#define MPAD 4096

#define NBLK 256

// async global->LDS, 16B per lane, wave-uniform LDS base
__device__ __forceinline__ void g2lds16(const bf16_t* g, bf16_t* l) {
  __builtin_amdgcn_global_load_lds((const __attribute__((address_space(1))) void*)g,
                                   (__attribute__((address_space(3))) void*)l, 16, 0, 0);
}

__device__ __forceinline__ unsigned short bf16bits(float x) {
  bf16_t b = (bf16_t)x;
  return __builtin_bit_cast(unsigned short, b);
}

// ---------------- prep: casts, gather, zeroing ----------------
__global__ void k_prep(const int* __restrict__ idx, const float* __restrict__ emb,
                       const float* __restrict__ W_ih, const float* __restrict__ W_hh,
                       const float* __restrict__ b_ih, const float* __restrict__ b_hh,
                       const float* __restrict__ W_out, const float* __restrict__ h0,
                       bf16_t* __restrict__ W_ih_bf, bf16_t* __restrict__ W_hh_bf,
                       bf16_t* __restrict__ W_out_bf, bf16_t* __restrict__ x_bf,
                       bf16_t* __restrict__ h_all, bf16_t* __restrict__ h0_bf,
                       float* __restrict__ bc, float* __restrict__ rowS,
                       int* __restrict__ tgt, unsigned* __restrict__ bar) {
  const long nW_ih = 4096L * 512;
  const long nW_hh = 4096L * 1024;
  const long nW_out = 32000L * 1024;
  const long nX = 4096L * 512;
  const long nH0 = 32L * 1024;
  const long nHpad = 32L * 1024;
  const long NTOTAL = nW_ih + nW_hh + nW_out + nX + nH0 + nHpad + 3 * 4096L + 1024;
  long stride = (long)gridDim.x * blockDim.x;
  for (long i = (long)blockIdx.x * blockDim.x + threadIdx.x; i < NTOTAL; i += stride) {
    long j = i;
    if (j < nW_ih) { W_ih_bf[j] = (bf16_t)W_ih[j]; continue; }
    j -= nW_ih;
    if (j < nW_hh) { W_hh_bf[j] = (bf16_t)W_hh[j]; continue; }
    j -= nW_hh;
    if (j < nW_out) { W_out_bf[j] = (bf16_t)W_out[j]; continue; }
    j -= nW_out;
    if (j < nX) {
      long m = j >> 9; int e = (int)(j & 511);
      float x = 0.f;
      if (m < MROWS) { x = emb[(long)idx[m] * NE + e]; x = x > 0.f ? x : 0.f; }
      x_bf[j] = (bf16_t)x; continue;
    }
    j -= nX;
    if (j < nH0) { h0_bf[j] = (bf16_t)h0[j]; continue; }
    j -= nH0;
    if (j < nHpad) { h_all[4161536L + j] = (bf16_t)0.f; continue; }  // pad rows 4064..4095
    j -= nHpad;
    if (j < 4096) { bc[j] = b_ih[j] + b_hh[j]; continue; }
    j -= 4096;
    if (j < 4096) { rowS[j] = 0.f; continue; }
    j -= 4096;
    if (j < 4096) { tgt[j] = (j < MROWS) ? idx[j + NB] : 0; continue; }
    j -= 4096;
    { bar[j] = 0u; continue; }
  }
}

// ---------------- GEMM1: gates_x = x @ W_ih^T + (b_ih+b_hh), bf16 out ----------------
__global__ __launch_bounds__(256) void k_gemm1(const bf16_t* __restrict__ A,
                                               const bf16_t* __restrict__ B,
                                               const float* __restrict__ bc,
                                               bf16_t* __restrict__ C) {
  const int K = 512;
  int tid = threadIdx.x, wid = tid >> 6, lane = tid & 63;
  int wm = wid & 1, wn = wid >> 1;
  int quad = lane >> 4, l15 = lane & 15;
  int mBase = blockIdx.x * 64, nBase = blockIdx.y * 128;

  const bf16x8* pa0 = (const bf16x8*)(A + (long)(mBase + wm * 32 + l15) * K + quad * 8);
  const bf16x8* pa1 = (const bf16x8*)(A + (long)(mBase + wm * 32 + 16 + l15) * K + quad * 8);
  const bf16x8* pb[4];
#pragma unroll
  for (int j = 0; j < 4; ++j)
    pb[j] = (const bf16x8*)(B + (long)(nBase + wn * 64 + j * 16 + l15) * K + quad * 8);

  f32x4 acc[2][4];
#pragma unroll
  for (int mi = 0; mi < 2; ++mi)
#pragma unroll
    for (int ni = 0; ni < 4; ++ni) acc[mi][ni] = (f32x4){0.f, 0.f, 0.f, 0.f};

  for (int kk = 0; kk < K / 32; ++kk) {
    bf16x8 a0 = pa0[kk * 4], a1 = pa1[kk * 4];
    bf16x8 b0 = pb[0][kk * 4], b1 = pb[1][kk * 4], b2 = pb[2][kk * 4], b3 = pb[3][kk * 4];
    acc[0][0] = __builtin_amdgcn_mfma_f32_16x16x32_bf16(a0, b0, acc[0][0], 0, 0, 0);
    acc[0][1] = __builtin_amdgcn_mfma_f32_16x16x32_bf16(a0, b1, acc[0][1], 0, 0, 0);
    acc[0][2] = __builtin_amdgcn_mfma_f32_16x16x32_bf16(a0, b2, acc[0][2], 0, 0, 0);
    acc[0][3] = __builtin_amdgcn_mfma_f32_16x16x32_bf16(a0, b3, acc[0][3], 0, 0, 0);
    acc[1][0] = __builtin_amdgcn_mfma_f32_16x16x32_bf16(a1, b0, acc[1][0], 0, 0, 0);
    acc[1][1] = __builtin_amdgcn_mfma_f32_16x16x32_bf16(a1, b1, acc[1][1], 0, 0, 0);
    acc[1][2] = __builtin_amdgcn_mfma_f32_16x16x32_bf16(a1, b2, acc[1][2], 0, 0, 0);
    acc[1][3] = __builtin_amdgcn_mfma_f32_16x16x32_bf16(a1, b3, acc[1][3], 0, 0, 0);
  }
#pragma unroll
  for (int ni = 0; ni < 4; ++ni) {
    int col = nBase + wn * 64 + ni * 16 + l15;
    float bcv = bc[col];
#pragma unroll
    for (int mi = 0; mi < 2; ++mi)
#pragma unroll
      for (int r = 0; r < 4; ++r) {
        int row = mBase + wm * 32 + mi * 16 + quad * 4 + r;
        C[(long)row * G4 + col] = (bf16_t)(acc[mi][ni][r] + bcv);
      }
  }
}

// ---------------- LSTM recurrence v8: write-once flags, aggregator folded into wave 7 ----------------
// 256 blocks x 512 threads (proven cooperative config). Same sync design as v7
// but without the 9th wave: wave 7 of blocks 0/1 performs the per-half
// aggregation at the top of each step (it is idle there anyway — only wave 0
// does pointwise). Chain per step:
//   producer wave0: h stores -> vmcnt(0) -> ONE write-once flag store
//   aggregator (wave7, blocks 0/1): coalesced dwordx2 poll of 128 flags
//                                   (s_sleep-paced, 2 waves chip-wide)
//                                   -> ONE write-once gen store
//   consumers: thread0 sleep-paced poll of gen (v4's proven pattern)
// Invariants from v4(602) vs v5(735)/v6(750): polled cells are write-once,
// pollers few+paced, producers never RMW a polled line. No dependency cycles:
// flag(t) is stored after barrier2(t-1) regardless of aggregator progress.
// Kept from v6 (validated): red stride 68 (conflict-free read), 2 barriers/step
// (red(t+1) writes occur after barrier1(t+1), which wave0 reaches only after
// pointwise(t) -> single red buffer safe).
__global__ __launch_bounds__(512) void k_rec8(const bf16_t* __restrict__ gates_x,
                                              const bf16_t* __restrict__ W_hh_bf,
                                              const bf16_t* __restrict__ h0_bf,
                                              bf16_t* __restrict__ h_all,
                                              const float* __restrict__ c0,
                                              unsigned* __restrict__ bar) {
  __shared__ __align__(16) float red[32 * 68];  // row stride 68 floats

  int bid = blockIdx.x;
  int mi = bid & 1;              // batch half
  int hb = bid >> 1;             // 0..127 within half
  int gbase = hb * 8;            // first hidden unit owned by this block
  int tid = threadIdx.x, wid = tid >> 6, lane = tid & 63;
  int cg = wid & 1, kh = wid >> 1;
  int quad = lane >> 4, l15 = lane & 15;

  unsigned* genp = bar + mi * 512 + 288;          // write-once/step, poll target
  unsigned* flagp = bar + mi * 512 + 320 + hb;    // this block's write-once flag
  const unsigned* fp2 = bar + mi * 512 + 320 + (lane << 1);  // aggregator view
  bool isagg = (bid < 2) && (wid == 7);

  int wrow = (cg ? 2048 : 0) + ((l15 & 8) ? 1024 : 0) + gbase + (l15 & 7);
  const bf16x8* pw = (const bf16x8*)(W_hh_bf + (long)wrow * NH + kh * 256 + quad * 8);
  bf16x8 wfrag[8];
#pragma unroll
  for (int kk = 0; kk < 8; ++kk) wfrag[kk] = pw[kk * 4];  // resident in VGPRs

  // pointwise: threads 0..63 (wave 0): b = tid>>2, unit pair = (tid&3)*2
  int pb = tid >> 2, pu2 = (tid & 3) * 2;
  int u0 = gbase + pu2;
  int bglob = mi * 16 + pb;
  float cst0 = 0.f, cst1 = 0.f;
  if (tid < 64) {
    cst0 = c0[(long)bglob * NH + u0];
    cst1 = c0[(long)bglob * NH + u0 + 1];
  }
  unsigned* h32 = (unsigned*)h_all;

  for (int t = 0; t < T_SEQ - 1; ++t) {
    // prefetch gates_x pairs (independent of h_prev; overlaps gen wait)
    unsigned gxi2 = 0, gxf2 = 0, gxg2 = 0, gxo2 = 0;
    if (tid < 64) {
      const unsigned* gp = (const unsigned*)(gates_x + (long)(t * NB + bglob) * G4);
      int q = u0 >> 1;
      gxi2 = gp[q]; gxf2 = gp[512 + q]; gxg2 = gp[1024 + q]; gxo2 = gp[1536 + q];
    }

    if (t > 0) {
      // per-half aggregator: wave 7 of blocks 0/1 polls all 128 write-once
      // flags (one coalesced dwordx2/lane) and publishes gen with ONE store
      if (isagg) {
        unsigned need = (unsigned)t;
        while (1) {
          u32x2 fv;
          asm volatile("global_load_dwordx2 %0, %1, off sc0 sc1\n\t"
                       "s_waitcnt vmcnt(0)"
                       : "=&v"(fv) : "v"(fp2) : "memory");
          if (__all((fv.x >= need) & (fv.y >= need))) break;
          __builtin_amdgcn_s_sleep(1);
        }
        if (lane == 0)
          __hip_atomic_store(genp, (unsigned)t, __ATOMIC_RELAXED,
                             __HIP_MEMORY_SCOPE_AGENT);
      }
      // v4-style consumer detect: thread0 sleep-paced poll on write-once gen
      if (tid == 0) {
        unsigned need = (unsigned)t;
        while (__hip_atomic_load(genp, __ATOMIC_RELAXED,
                                 __HIP_MEMORY_SCOPE_AGENT) < need)
          __builtin_amdgcn_s_sleep(1);
      }
    }
    __syncthreads();  // barrier1: release block; also covers red anti-dep
    asm volatile("" ::: "memory");

    const bf16_t* hp = (t == 0) ? h0_bf : (h_all + (long)(t - 1) * NB * NH);
    const bf16x8* pa = (const bf16x8*)(hp + (long)(mi * 16 + l15) * NH + kh * 256 + quad * 8);
    f32x4 acc = (f32x4){0.f, 0.f, 0.f, 0.f};
#pragma unroll
    for (int kk = 0; kk < 8; ++kk) {
      bf16x8 a = pa[kk * 4];
      acc = __builtin_amdgcn_mfma_f32_16x16x32_bf16(a, wfrag[kk], acc, 0, 0, 0);
    }
#pragma unroll
    for (int r = 0; r < 4; ++r) {
      int row = (cg << 4) + (quad << 2) + r;
      red[row * 68 + (l15 << 2) + kh] = acc[r];
    }
    __syncthreads();  // barrier2: red ready

    if (tid < 64) {
      const float* rc = red;
      float hv[2];
#pragma unroll
      for (int d = 0; d < 2; ++d) {
        int q = pu2 + d;
        float4 vi = *(const float4*)(rc + pb * 68 + (q << 2));
        float4 vf = *(const float4*)(rc + pb * 68 + ((8 + q) << 2));
        float4 vg = *(const float4*)(rc + (16 + pb) * 68 + (q << 2));
        float4 vo = *(const float4*)(rc + (16 + pb) * 68 + ((8 + q) << 2));
        unsigned bi = d ? (gxi2 & 0xffff0000u) : (gxi2 << 16);
        unsigned bff = d ? (gxf2 & 0xffff0000u) : (gxf2 << 16);
        unsigned bg = d ? (gxg2 & 0xffff0000u) : (gxg2 << 16);
        unsigned bo = d ? (gxo2 & 0xffff0000u) : (gxo2 << 16);
        float iv = vi.x + vi.y + vi.z + vi.w + __builtin_bit_cast(float, bi);
        float fv = vf.x + vf.y + vf.z + vf.w + __builtin_bit_cast(float, bff);
        float gv = vg.x + vg.y + vg.z + vg.w + __builtin_bit_cast(float, bg);
        float ov = vo.x + vo.y + vo.z + vo.w + __builtin_bit_cast(float, bo);
        float si = 1.f / (1.f + __expf(-iv));
        float sf = 1.f / (1.f + __expf(-fv));
        float so = 1.f / (1.f + __expf(-ov));
        float tg = 1.f - 2.f / (__expf(2.f * gv) + 1.f);
        float& cs = d ? cst1 : cst0;
        cs = sf * cs + si * tg;
        float th = 1.f - 2.f / (__expf(2.f * cs) + 1.f);
        hv[d] = so * th;
      }
      unsigned pack = (unsigned)bf16bits(hv[0]) | ((unsigned)bf16bits(hv[1]) << 16);
      // agent-scope write-through store: visible at LLC, no L2 dirty line
      __hip_atomic_store(&h32[(long)(t * NB + bglob) * 512 + (u0 >> 1)], pack,
                         __ATOMIC_RELAXED, __HIP_MEMORY_SCOPE_AGENT);
      if (t < T_SEQ - 2) {
        asm volatile("" ::: "memory");
        if (tid == 0) {
          __builtin_amdgcn_s_waitcnt(0x0f70);  // vmcnt(0): wave0 h stores acked at LLC
          asm volatile("" ::: "memory");
          // single write-once plain store replaces v4's grp->root->gen RMW tree
          __hip_atomic_store(flagp, (unsigned)(t + 1), __ATOMIC_RELAXED,
                             __HIP_MEMORY_SCOPE_AGENT);
        }
      }
    }
  }
}

// ---------------- GEMM2 v2: m97-style LDS-staged, exp-rowsum epilogue ----------------
__global__ __launch_bounds__(256) void k_gemm2(const bf16_t* __restrict__ A,
                                               const bf16_t* __restrict__ B,
                                               const float* __restrict__ b_out,
                                               float* __restrict__ rowS) {
  __shared__ bf16_t As[128 * 32];
  __shared__ bf16_t Bs[128 * 32];
  const int K = 1024;
  int tid = threadIdx.x, wid = tid >> 6, lane = tid & 63;
  int wm = wid & 1, wn = wid >> 1;
  int quad = lane >> 4, l15 = lane & 15;
  int mBase = blockIdx.x * 128, nBase = blockIdx.y * 128;

  int rc = lane >> 2, seg = lane & 3;
  int cA0 = 2 * wid, cA1 = 2 * wid + 1;
  const bf16_t* gA0 = A + (size_t)(mBase + cA0 * 16 + rc) * K + seg * 8;
  const bf16_t* gA1 = A + (size_t)(mBase + cA1 * 16 + rc) * K + seg * 8;
  const bf16_t* gB0 = B + (size_t)(nBase + cA0 * 16 + rc) * K + seg * 8;
  const bf16_t* gB1 = B + (size_t)(nBase + cA1 * 16 + rc) * K + seg * 8;
  bf16_t* lA0 = As + cA0 * 512;
  bf16_t* lA1 = As + cA1 * 512;
  bf16_t* lB0 = Bs + cA0 * 512;
  bf16_t* lB1 = Bs + cA1 * 512;

  const bf16x8* pa[4];
  const bf16x8* pbf[4];
#pragma unroll
  for (int i = 0; i < 4; ++i) {
    pa[i] = (const bf16x8*)(As + (wm * 64 + i * 16 + l15) * 32 + quad * 8);
    pbf[i] = (const bf16x8*)(Bs + (wn * 64 + i * 16 + l15) * 32 + quad * 8);
  }

  f32x4 acc[4][4];
#pragma unroll
  for (int i = 0; i < 4; ++i)
#pragma unroll
    for (int j = 0; j < 4; ++j) acc[i][j] = (f32x4){0.f, 0.f, 0.f, 0.f};

  for (int kt = 0; kt < K / 32; ++kt) {
    g2lds16(gA0 + kt * 32, lA0);
    g2lds16(gA1 + kt * 32, lA1);
    g2lds16(gB0 + kt * 32, lB0);
    g2lds16(gB1 + kt * 32, lB1);
    __syncthreads();

    bf16x8 af[4], bf[4];
#pragma unroll
    for (int i = 0; i < 4; ++i) { af[i] = *pa[i]; bf[i] = *pbf[i]; }
#pragma unroll
    for (int i = 0; i < 4; ++i)
#pragma unroll
      for (int j = 0; j < 4; ++j)
        acc[i][j] = __builtin_amdgcn_mfma_f32_16x16x32_bf16(af[i], bf[j], acc[i][j], 0, 0, 0);
    __syncthreads();
  }

#pragma unroll
  for (int i = 0; i < 4; ++i) {
    float rs[4] = {0.f, 0.f, 0.f, 0.f};
#pragma unroll
    for (int j = 0; j < 4; ++j) {
      int col = nBase + wn * 64 + j * 16 + l15;
      float bb = b_out[col];
#pragma unroll
      for (int r = 0; r < 4; ++r) rs[r] += __expf(acc[i][j][r] + bb);
    }
#pragma unroll
    for (int r = 0; r < 4; ++r) {
#pragma unroll
      for (int s = 1; s < 16; s <<= 1) rs[r] += __shfl_xor(rs[r], s);
      if (l15 == 0) {
        int row = mBase + wm * 64 + i * 16 + quad * 4 + r;
        if (row < MROWS) atomicAdd(&rowS[row], rs[r]);
      }
    }
  }
}

// ---------------- target logits ----------------
__global__ __launch_bounds__(256) void k_tgt(const bf16_t* __restrict__ h_all,
                                             const bf16_t* __restrict__ W_out_bf,
                                             const float* __restrict__ b_out,
                                             const int* __restrict__ tgt,
                                             float* __restrict__ tgt_logit) {
  int gw = (int)((blockIdx.x * blockDim.x + threadIdx.x) >> 6);
  int lane = threadIdx.x & 63;
  if (gw >= MROWS) return;
  int v = tgt[gw];
  const bf16x8* ph = (const bf16x8*)(h_all + (long)gw * NH + lane * 16);
  const bf16x8* pw = (const bf16x8*)(W_out_bf + (long)v * NH + lane * 16);
  float acc = 0.f;
#pragma unroll
  for (int j = 0; j < 2; ++j) {
    bf16x8 h8 = ph[j], w8 = pw[j];
#pragma unroll
    for (int q = 0; q < 8; ++q) acc += (float)h8[q] * (float)w8[q];
  }
#pragma unroll
  for (int s = 1; s < 64; s <<= 1) acc += __shfl_xor(acc, s);
  if (lane == 0) tgt_logit[gw] = acc + b_out[v];
}

// ---------------- final loss reduction ----------------
__global__ __launch_bounds__(256) void k_loss(const float* __restrict__ rowS,
                                              const float* __restrict__ tl,
                                              const int* __restrict__ tgt,
                                              float* __restrict__ out) {
  __shared__ float sm[256];
  float s = 0.f;
  for (int i = threadIdx.x; i < MROWS; i += 256)
    if (tgt[i] != 0) s += logf(rowS[i]) - tl[i];
  sm[threadIdx.x] = s;
  __syncthreads();
  for (int off = 128; off > 0; off >>= 1) {
    if (threadIdx.x < off) sm[threadIdx.x] += sm[threadIdx.x + off];
    __syncthreads();
  }
  if (threadIdx.x == 0) out[0] = sm[0];
}

extern "C" void kernel_launch(void* const* d_in, const int* in_sizes, int n_in,
                              void* d_out, int out_size, void* d_ws, size_t ws_size,
                              hipStream_t stream) {
  const int* idx = (const int*)d_in[0];
  const float* emb = (const float*)d_in[1];
  const float* W_ih = (const float*)d_in[2];
  const float* W_hh = (const float*)d_in[3];
  const float* b_ih = (const float*)d_in[4];
  const float* b_hh = (const float*)d_in[5];
  const float* W_out = (const float*)d_in[6];
  const float* b_out = (const float*)d_in[7];
  const float* h0 = (const float*)d_in[8];
  const float* c0 = (const float*)d_in[9];

  char* ws = (char*)d_ws;
  bf16_t* W_ih_bf = (bf16_t*)ws;            ws += 4096L * 512 * 2;
  bf16_t* W_hh_bf = (bf16_t*)ws;            ws += 4096L * 1024 * 2;
  bf16_t* W_out_bf = (bf16_t*)ws;           ws += 32000L * 1024 * 2;
  bf16_t* x_bf = (bf16_t*)ws;               ws += 4096L * 512 * 2;
  bf16_t* gates_x = (bf16_t*)ws;            ws += 4096L * 4096 * 2;
  bf16_t* h_all = (bf16_t*)ws;              ws += 4096L * 1024 * 2;
  bf16_t* h0_bf = (bf16_t*)ws;              ws += 32L * 1024 * 2;
  float* bc = (float*)ws;                   ws += 4096L * 4;
  float* rowS = (float*)ws;                 ws += 4096L * 4;
  float* tgt_logit = (float*)ws;            ws += 4096L * 4;
  int* tgt = (int*)ws;                      ws += 4096L * 4;
  unsigned* bar = (unsigned*)ws;            ws += 1024L * 4;

  k_prep<<<4096, 256, 0, stream>>>(idx, emb, W_ih, W_hh, b_ih, b_hh, W_out, h0,
                                   W_ih_bf, W_hh_bf, W_out_bf, x_bf, h_all, h0_bf,
                                   bc, rowS, tgt, bar);

  k_gemm1<<<dim3(64, 32), 256, 0, stream>>>(x_bf, W_ih_bf, bc, gates_x);

  {
    void* args[] = {(void*)&gates_x, (void*)&W_hh_bf, (void*)&h0_bf, (void*)&h_all,
                    (void*)&c0, (void*)&bar};
    hipLaunchCooperativeKernel((void*)k_rec8, dim3(NBLK), dim3(512), args, 0, stream);
  }

  k_gemm2<<<dim3(32, 250), 256, 0, stream>>>(h_all, W_out_bf, b_out, rowS);

  k_tgt<<<1016, 256, 0, stream>>>(h_all, W_out_bf, b_out, tgt, tgt_logit);

  k_loss<<<1, 256, 0, stream>>>(rowS, tgt_logit, tgt, (float*)d_out);
}

// Round 5
// 1261.379 us; speedup vs baseline: 1.1664x; 1.0560x over previous
//
#include <hip/hip_runtime.h>
#include <hip/hip_bf16.h>
#include <hip/hip_cooperative_groups.h>
#include <math.h>

namespace cg = cooperative_groups;

typedef __bf16 bf16_t;
typedef bf16_t bf16x8 __attribute__((ext_vector_type(8)));
typedef float f32x4 __attribute__((ext_vector_type(4)));
typedef unsigned u32x2 __attribute__((ext_vector_type(2)));
typedef unsigned u32x4 __attribute__((ext_vector_type(4)));

#define T_SEQ 128
#define NB 32
#define NV 32000
#define NE 512
#define NH 1024
#define G4 4096          // 4*NH
#define MROWS 4064       // 127*32
#define MPAD 4096

#define NBLK 256
#define SENT 0xFFFFFFFFu  // two bf16 NaNs; h = sig*tanh is always finite

// async global->LDS, 16B per lane, wave-uniform LDS base
__device__ __forceinline__ void g2lds16(const bf16_t* g, bf16_t* l) {
  __builtin_amdgcn_global_load_lds((const __attribute__((address_space(1))) void*)g,
                                   (__attribute__((address_space(3))) void*)l, 16, 0, 0);
}

__device__ __forceinline__ unsigned short bf16bits(float x) {
  bf16_t b = (bf16_t)x;
  return __builtin_bit_cast(unsigned short, b);
}

__device__ __forceinline__ void cvt4(const float* __restrict__ s,
                                     bf16_t* __restrict__ d, long j) {
  float4 v = *(const float4*)(s + j * 4);
  uint2 o;
  o.x = (unsigned)bf16bits(v.x) | ((unsigned)bf16bits(v.y) << 16);
  o.y = (unsigned)bf16bits(v.z) | ((unsigned)bf16bits(v.w) << 16);
  *(uint2*)(d + j * 4) = o;
}

// ---------------- prep v2: vectorized casts/gather + h_all sentinel init ----------------
__global__ void k_prep(const int* __restrict__ idx, const float* __restrict__ emb,
                       const float* __restrict__ W_ih, const float* __restrict__ W_hh,
                       const float* __restrict__ b_ih, const float* __restrict__ b_hh,
                       const float* __restrict__ W_out, const float* __restrict__ h0,
                       bf16_t* __restrict__ W_ih_bf, bf16_t* __restrict__ W_hh_bf,
                       bf16_t* __restrict__ W_out_bf, bf16_t* __restrict__ x_bf,
                       bf16_t* __restrict__ h_all, bf16_t* __restrict__ h0_bf,
                       float* __restrict__ bc, float* __restrict__ rowS,
                       int* __restrict__ tgt, unsigned* __restrict__ bar) {
  const long n4_Wih = 4096L * 512 / 4;     // 524288 float4
  const long n4_Whh = 4096L * 1024 / 4;    // 1048576
  const long n4_Wout = 32000L * 1024 / 4;  // 8192000
  const long n4_X = 4096L * 512 / 4;       // 524288
  const long n4_H0 = 32L * 1024 / 4;       // 8192
  const long n4_Hall = 4096L * 1024 / 8;   // 524288 uint4 over all of h_all
  const long nSentinel = 4064L * 128;      // 520192 uint4 = rows 0..4063
  const long nScal = 3 * 4096L + 1024;
  const long NTOT = n4_Wih + n4_Whh + n4_Wout + n4_X + n4_H0 + n4_Hall + nScal;
  long stride = (long)gridDim.x * blockDim.x;
  for (long i = (long)blockIdx.x * blockDim.x + threadIdx.x; i < NTOT; i += stride) {
    long j = i;
    if (j < n4_Wih) { cvt4(W_ih, W_ih_bf, j); continue; }
    j -= n4_Wih;
    if (j < n4_Whh) { cvt4(W_hh, W_hh_bf, j); continue; }
    j -= n4_Whh;
    if (j < n4_Wout) { cvt4(W_out, W_out_bf, j); continue; }
    j -= n4_Wout;
    if (j < n4_X) {
      long m = j >> 7; int e4 = (int)(j & 127);
      uint2 o; o.x = 0u; o.y = 0u;
      if (m < MROWS) {
        float4 v = *(const float4*)(emb + (long)idx[m] * NE + e4 * 4);
        v.x = fmaxf(v.x, 0.f); v.y = fmaxf(v.y, 0.f);
        v.z = fmaxf(v.z, 0.f); v.w = fmaxf(v.w, 0.f);
        o.x = (unsigned)bf16bits(v.x) | ((unsigned)bf16bits(v.y) << 16);
        o.y = (unsigned)bf16bits(v.z) | ((unsigned)bf16bits(v.w) << 16);
      }
      *(uint2*)(x_bf + m * 512 + e4 * 4) = o;
      continue;
    }
    j -= n4_X;
    if (j < n4_H0) { cvt4(h0, h0_bf, j); continue; }
    j -= n4_H0;
    if (j < n4_Hall) {
      // rows 0..4063: sentinel (never a valid packed h pair); pad rows: zero
      unsigned v = (j < nSentinel) ? SENT : 0u;
      uint4 s; s.x = v; s.y = v; s.z = v; s.w = v;
      ((uint4*)h_all)[j] = s;
      continue;
    }
    j -= n4_Hall;
    if (j < 4096) { bc[j] = b_ih[j] + b_hh[j]; continue; }
    j -= 4096;
    if (j < 4096) { rowS[j] = 0.f; continue; }
    j -= 4096;
    if (j < 4096) { tgt[j] = (j < MROWS) ? idx[j + NB] : 0; continue; }
    j -= 4096;
    { bar[j] = 0u; continue; }
  }
}

// ---------------- GEMM1: gates_x = x @ W_ih^T + (b_ih+b_hh), bf16 out ----------------
__global__ __launch_bounds__(256) void k_gemm1(const bf16_t* __restrict__ A,
                                               const bf16_t* __restrict__ B,
                                               const float* __restrict__ bc,
                                               bf16_t* __restrict__ C) {
  const int K = 512;
  int tid = threadIdx.x, wid = tid >> 6, lane = tid & 63;
  int wm = wid & 1, wn = wid >> 1;
  int quad = lane >> 4, l15 = lane & 15;
  int mBase = blockIdx.x * 64, nBase = blockIdx.y * 128;

  const bf16x8* pa0 = (const bf16x8*)(A + (long)(mBase + wm * 32 + l15) * K + quad * 8);
  const bf16x8* pa1 = (const bf16x8*)(A + (long)(mBase + wm * 32 + 16 + l15) * K + quad * 8);
  const bf16x8* pb[4];
#pragma unroll
  for (int j = 0; j < 4; ++j)
    pb[j] = (const bf16x8*)(B + (long)(nBase + wn * 64 + j * 16 + l15) * K + quad * 8);

  f32x4 acc[2][4];
#pragma unroll
  for (int mi = 0; mi < 2; ++mi)
#pragma unroll
    for (int ni = 0; ni < 4; ++ni) acc[mi][ni] = (f32x4){0.f, 0.f, 0.f, 0.f};

  for (int kk = 0; kk < K / 32; ++kk) {
    bf16x8 a0 = pa0[kk * 4], a1 = pa1[kk * 4];
    bf16x8 b0 = pb[0][kk * 4], b1 = pb[1][kk * 4], b2 = pb[2][kk * 4], b3 = pb[3][kk * 4];
    acc[0][0] = __builtin_amdgcn_mfma_f32_16x16x32_bf16(a0, b0, acc[0][0], 0, 0, 0);
    acc[0][1] = __builtin_amdgcn_mfma_f32_16x16x32_bf16(a0, b1, acc[0][1], 0, 0, 0);
    acc[0][2] = __builtin_amdgcn_mfma_f32_16x16x32_bf16(a0, b2, acc[0][2], 0, 0, 0);
    acc[0][3] = __builtin_amdgcn_mfma_f32_16x16x32_bf16(a0, b3, acc[0][3], 0, 0, 0);
    acc[1][0] = __builtin_amdgcn_mfma_f32_16x16x32_bf16(a1, b0, acc[1][0], 0, 0, 0);
    acc[1][1] = __builtin_amdgcn_mfma_f32_16x16x32_bf16(a1, b1, acc[1][1], 0, 0, 0);
    acc[1][2] = __builtin_amdgcn_mfma_f32_16x16x32_bf16(a1, b2, acc[1][2], 0, 0, 0);
    acc[1][3] = __builtin_amdgcn_mfma_f32_16x16x32_bf16(a1, b3, acc[1][3], 0, 0, 0);
  }
#pragma unroll
  for (int ni = 0; ni < 4; ++ni) {
    int col = nBase + wn * 64 + ni * 16 + l15;
    float bcv = bc[col];
#pragma unroll
    for (int mi = 0; mi < 2; ++mi)
#pragma unroll
      for (int r = 0; r < 4; ++r) {
        int row = mBase + wm * 32 + mi * 16 + quad * 4 + r;
        C[(long)row * G4 + col] = (bf16_t)(acc[mi][ni][r] + bcv);
      }
  }
}

// ---------------- LSTM recurrence v9: sentinel-validated h, ack removed ----------------
// 256 blocks x 512 threads. vs v8 (600us == v4's 602): the producer-side
// vmcnt(0) store-ack is REMOVED from the signal chain. h_all is pre-filled
// with 0xFFFFFFFF sentinels (unreachable bit pattern: h=sig*tanh is finite);
// correctness no longer depends on flag/data ordering — consumers validate
// the data itself. The v8 flag->aggregator->gen machinery is kept purely as
// PACING (few, sleep-paced pollers on write-once cells — the invariants that
// separated 600us designs from 735/750us ones). Consumers load h PLAIN first
// (keeps L2 sharing; by gen-detect time h has nearly always landed) and fall
// into a rare sc0sc1+sentinel retry loop otherwise.
__global__ __launch_bounds__(512) void k_rec9(const bf16_t* __restrict__ gates_x,
                                              const bf16_t* __restrict__ W_hh_bf,
                                              const bf16_t* __restrict__ h0_bf,
                                              bf16_t* __restrict__ h_all,
                                              const float* __restrict__ c0,
                                              unsigned* __restrict__ bar) {
  __shared__ __align__(16) float red[32 * 68];  // row stride 68 floats

  int bid = blockIdx.x;
  int mi = bid & 1;              // batch half
  int hb = bid >> 1;             // 0..127 within half
  int gbase = hb * 8;            // first hidden unit owned by this block
  int tid = threadIdx.x, wid = tid >> 6, lane = tid & 63;
  int cg = wid & 1, kh = wid >> 1;
  int quad = lane >> 4, l15 = lane & 15;

  unsigned* genp = bar + mi * 512 + 288;          // write-once/step, poll target
  unsigned* flagp = bar + mi * 512 + 320 + hb;    // this block's write-once flag
  const unsigned* fp2 = bar + mi * 512 + 320 + (lane << 1);  // aggregator view
  bool isagg = (bid < 2) && (wid == 7);

  int wrow = (cg ? 2048 : 0) + ((l15 & 8) ? 1024 : 0) + gbase + (l15 & 7);
  const bf16x8* pw = (const bf16x8*)(W_hh_bf + (long)wrow * NH + kh * 256 + quad * 8);
  bf16x8 wfrag[8];
#pragma unroll
  for (int kk = 0; kk < 8; ++kk) wfrag[kk] = pw[kk * 4];  // resident in VGPRs

  // pointwise: threads 0..63 (wave 0): b = tid>>2, unit pair = (tid&3)*2
  int pb = tid >> 2, pu2 = (tid & 3) * 2;
  int u0 = gbase + pu2;
  int bglob = mi * 16 + pb;
  float cst0 = 0.f, cst1 = 0.f;
  if (tid < 64) {
    cst0 = c0[(long)bglob * NH + u0];
    cst1 = c0[(long)bglob * NH + u0 + 1];
  }
  unsigned* h32 = (unsigned*)h_all;

  for (int t = 0; t < T_SEQ - 1; ++t) {
    // prefetch gates_x pairs (independent of h_prev; overlaps gen wait)
    unsigned gxi2 = 0, gxf2 = 0, gxg2 = 0, gxo2 = 0;
    if (tid < 64) {
      const unsigned* gp = (const unsigned*)(gates_x + (long)(t * NB + bglob) * G4);
      int q = u0 >> 1;
      gxi2 = gp[q]; gxf2 = gp[512 + q]; gxg2 = gp[1024 + q]; gxo2 = gp[1536 + q];
    }

    if (t > 0) {
      // per-half aggregator: wave 7 of blocks 0/1 polls all 128 write-once
      // flags (one coalesced dwordx2/lane) and publishes gen with ONE store
      if (isagg) {
        unsigned need = (unsigned)t;
        while (1) {
          u32x2 fv;
          asm volatile("global_load_dwordx2 %0, %1, off sc0 sc1\n\t"
                       "s_waitcnt vmcnt(0)"
                       : "=&v"(fv) : "v"(fp2) : "memory");
          if (__all((fv.x >= need) & (fv.y >= need))) break;
          __builtin_amdgcn_s_sleep(1);
        }
        if (lane == 0)
          __hip_atomic_store(genp, (unsigned)t, __ATOMIC_RELAXED,
                             __HIP_MEMORY_SCOPE_AGENT);
      }
      // consumer detect: thread0 sleep-paced poll on write-once gen
      if (tid == 0) {
        unsigned need = (unsigned)t;
        while (__hip_atomic_load(genp, __ATOMIC_RELAXED,
                                 __HIP_MEMORY_SCOPE_AGENT) < need)
          __builtin_amdgcn_s_sleep(1);
      }
    }
    __syncthreads();  // barrier1: release block; also covers red anti-dep
    asm volatile("" ::: "memory");

    bf16x8 hfr[8];
    if (t == 0) {
      const bf16x8* pa0 =
          (const bf16x8*)(h0_bf + (long)(mi * 16 + l15) * NH + kh * 256 + quad * 8);
#pragma unroll
      for (int kk = 0; kk < 8; ++kk) hfr[kk] = pa0[kk * 4];
    } else {
      const bf16_t* hb8 = h_all + (long)(t - 1) * NB * NH +
                          (long)(mi * 16 + l15) * NH + kh * 256 + quad * 8;
      const bf16x8* pa = (const bf16x8*)hb8;
#pragma unroll
      for (int kk = 0; kk < 8; ++kk) hfr[kk] = pa[kk * 4];  // plain (L2-shared)
      unsigned bad = 0;
#pragma unroll
      for (int kk = 0; kk < 8; ++kk) {
        u32x4 w = __builtin_bit_cast(u32x4, hfr[kk]);
        bad |= (unsigned)(w.x == SENT) | (unsigned)(w.y == SENT) |
               (unsigned)(w.z == SENT) | (unsigned)(w.w == SENT);
      }
      while (!__all(bad == 0)) {  // rare: data still in flight — coherent retry
        __builtin_amdgcn_s_sleep(1);
        u32x4 hw[8];
#pragma unroll
        for (int kk = 0; kk < 8; ++kk)
          asm volatile("global_load_dwordx4 %0, %1, off sc0 sc1"
                       : "=&v"(hw[kk]) : "v"(hb8 + kk * 32) : "memory");
        asm volatile("s_waitcnt vmcnt(0)" ::: "memory");
        bad = 0;
#pragma unroll
        for (int kk = 0; kk < 8; ++kk) {
          bad |= (unsigned)(hw[kk].x == SENT) | (unsigned)(hw[kk].y == SENT) |
                 (unsigned)(hw[kk].z == SENT) | (unsigned)(hw[kk].w == SENT);
          hfr[kk] = __builtin_bit_cast(bf16x8, hw[kk]);
        }
      }
    }

    f32x4 acc = (f32x4){0.f, 0.f, 0.f, 0.f};
#pragma unroll
    for (int kk = 0; kk < 8; ++kk)
      acc = __builtin_amdgcn_mfma_f32_16x16x32_bf16(hfr[kk], wfrag[kk], acc, 0, 0, 0);
#pragma unroll
    for (int r = 0; r < 4; ++r) {
      int row = (cg << 4) + (quad << 2) + r;
      red[row * 68 + (l15 << 2) + kh] = acc[r];
    }
    __syncthreads();  // barrier2: red ready

    if (tid < 64) {
      const float* rc = red;
      float hv[2];
#pragma unroll
      for (int d = 0; d < 2; ++d) {
        int q = pu2 + d;
        float4 vi = *(const float4*)(rc + pb * 68 + (q << 2));
        float4 vf = *(const float4*)(rc + pb * 68 + ((8 + q) << 2));
        float4 vg = *(const float4*)(rc + (16 + pb) * 68 + (q << 2));
        float4 vo = *(const float4*)(rc + (16 + pb) * 68 + ((8 + q) << 2));
        unsigned bi = d ? (gxi2 & 0xffff0000u) : (gxi2 << 16);
        unsigned bff = d ? (gxf2 & 0xffff0000u) : (gxf2 << 16);
        unsigned bg = d ? (gxg2 & 0xffff0000u) : (gxg2 << 16);
        unsigned bo = d ? (gxo2 & 0xffff0000u) : (gxo2 << 16);
        float iv = vi.x + vi.y + vi.z + vi.w + __builtin_bit_cast(float, bi);
        float fv = vf.x + vf.y + vf.z + vf.w + __builtin_bit_cast(float, bff);
        float gv = vg.x + vg.y + vg.z + vg.w + __builtin_bit_cast(float, bg);
        float ov = vo.x + vo.y + vo.z + vo.w + __builtin_bit_cast(float, bo);
        float si = 1.f / (1.f + __expf(-iv));
        float sf = 1.f / (1.f + __expf(-fv));
        float so = 1.f / (1.f + __expf(-ov));
        float tg = 1.f - 2.f / (__expf(2.f * gv) + 1.f);
        float& cs = d ? cst1 : cst0;
        cs = sf * cs + si * tg;
        float th = 1.f - 2.f / (__expf(2.f * cs) + 1.f);
        hv[d] = so * th;
      }
      unsigned pack = (unsigned)bf16bits(hv[0]) | ((unsigned)bf16bits(hv[1]) << 16);
      // agent-scope write-through store: visible at LLC, no L2 dirty line
      __hip_atomic_store(&h32[(long)(t * NB + bglob) * 512 + (u0 >> 1)], pack,
                         __ATOMIC_RELAXED, __HIP_MEMORY_SCOPE_AGENT);
      // flag immediately — NO store-ack. Ordering vs h is irrelevant:
      // consumers sentinel-validate the data itself.
      if (t < T_SEQ - 2 && tid == 0)
        __hip_atomic_store(flagp, (unsigned)(t + 1), __ATOMIC_RELAXED,
                           __HIP_MEMORY_SCOPE_AGENT);
    }
  }
}

// ---------------- GEMM2 v2: m97-style LDS-staged, exp-rowsum epilogue ----------------
__global__ __launch_bounds__(256) void k_gemm2(const bf16_t* __restrict__ A,
                                               const bf16_t* __restrict__ B,
                                               const float* __restrict__ b_out,
                                               float* __restrict__ rowS) {
  __shared__ bf16_t As[128 * 32];
  __shared__ bf16_t Bs[128 * 32];
  const int K = 1024;
  int tid = threadIdx.x, wid = tid >> 6, lane = tid & 63;
  int wm = wid & 1, wn = wid >> 1;
  int quad = lane >> 4, l15 = lane & 15;
  int mBase = blockIdx.x * 128, nBase = blockIdx.y * 128;

  int rc = lane >> 2, seg = lane & 3;
  int cA0 = 2 * wid, cA1 = 2 * wid + 1;
  const bf16_t* gA0 = A + (size_t)(mBase + cA0 * 16 + rc) * K + seg * 8;
  const bf16_t* gA1 = A + (size_t)(mBase + cA1 * 16 + rc) * K + seg * 8;
  const bf16_t* gB0 = B + (size_t)(nBase + cA0 * 16 + rc) * K + seg * 8;
  const bf16_t* gB1 = B + (size_t)(nBase + cA1 * 16 + rc) * K + seg * 8;
  bf16_t* lA0 = As + cA0 * 512;
  bf16_t* lA1 = As + cA1 * 512;
  bf16_t* lB0 = Bs + cA0 * 512;
  bf16_t* lB1 = Bs + cA1 * 512;

  const bf16x8* pa[4];
  const bf16x8* pbf[4];
#pragma unroll
  for (int i = 0; i < 4; ++i) {
    pa[i] = (const bf16x8*)(As + (wm * 64 + i * 16 + l15) * 32 + quad * 8);
    pbf[i] = (const bf16x8*)(Bs + (wn * 64 + i * 16 + l15) * 32 + quad * 8);
  }

  f32x4 acc[4][4];
#pragma unroll
  for (int i = 0; i < 4; ++i)
#pragma unroll
    for (int j = 0; j < 4; ++j) acc[i][j] = (f32x4){0.f, 0.f, 0.f, 0.f};

  for (int kt = 0; kt < K / 32; ++kt) {
    g2lds16(gA0 + kt * 32, lA0);
    g2lds16(gA1 + kt * 32, lA1);
    g2lds16(gB0 + kt * 32, lB0);
    g2lds16(gB1 + kt * 32, lB1);
    __syncthreads();

    bf16x8 af[4], bf[4];
#pragma unroll
    for (int i = 0; i < 4; ++i) { af[i] = *pa[i]; bf[i] = *pbf[i]; }
#pragma unroll
    for (int i = 0; i < 4; ++i)
#pragma unroll
      for (int j = 0; j < 4; ++j)
        acc[i][j] = __builtin_amdgcn_mfma_f32_16x16x32_bf16(af[i], bf[j], acc[i][j], 0, 0, 0);
    __syncthreads();
  }

#pragma unroll
  for (int i = 0; i < 4; ++i) {
    float rs[4] = {0.f, 0.f, 0.f, 0.f};
#pragma unroll
    for (int j = 0; j < 4; ++j) {
      int col = nBase + wn * 64 + j * 16 + l15;
      float bb = b_out[col];
#pragma unroll
      for (int r = 0; r < 4; ++r) rs[r] += __expf(acc[i][j][r] + bb);
    }
#pragma unroll
    for (int r = 0; r < 4; ++r) {
#pragma unroll
      for (int s = 1; s < 16; s <<= 1) rs[r] += __shfl_xor(rs[r], s);
      if (l15 == 0) {
        int row = mBase + wm * 64 + i * 16 + quad * 4 + r;
        if (row < MROWS) atomicAdd(&rowS[row], rs[r]);
      }
    }
  }
}

// ---------------- target logits ----------------
__global__ __launch_bounds__(256) void k_tgt(const bf16_t* __restrict__ h_all,
                                             const bf16_t* __restrict__ W_out_bf,
                                             const float* __restrict__ b_out,
                                             const int* __restrict__ tgt,
                                             float* __restrict__ tgt_logit) {
  int gw = (int)((blockIdx.x * blockDim.x + threadIdx.x) >> 6);
  int lane = threadIdx.x & 63;
  if (gw >= MROWS) return;
  int v = tgt[gw];
  const bf16x8* ph = (const bf16x8*)(h_all + (long)gw * NH + lane * 16);
  const bf16x8* pw = (const bf16x8*)(W_out_bf + (long)v * NH + lane * 16);
  float acc = 0.f;
#pragma unroll
  for (int j = 0; j < 2; ++j) {
    bf16x8 h8 = ph[j], w8 = pw[j];
#pragma unroll
    for (int q = 0; q < 8; ++q) acc += (float)h8[q] * (float)w8[q];
  }
#pragma unroll
  for (int s = 1; s < 64; s <<= 1) acc += __shfl_xor(acc, s);
  if (lane == 0) tgt_logit[gw] = acc + b_out[v];
}

// ---------------- final loss reduction ----------------
__global__ __launch_bounds__(256) void k_loss(const float* __restrict__ rowS,
                                              const float* __restrict__ tl,
                                              const int* __restrict__ tgt,
                                              float* __restrict__ out) {
  __shared__ float sm[256];
  float s = 0.f;
  for (int i = threadIdx.x; i < MROWS; i += 256)
    if (tgt[i] != 0) s += logf(rowS[i]) - tl[i];
  sm[threadIdx.x] = s;
  __syncthreads();
  for (int off = 128; off > 0; off >>= 1) {
    if (threadIdx.x < off) sm[threadIdx.x] += sm[threadIdx.x + off];
    __syncthreads();
  }
  if (threadIdx.x == 0) out[0] = sm[0];
}

extern "C" void kernel_launch(void* const* d_in, const int* in_sizes, int n_in,
                              void* d_out, int out_size, void* d_ws, size_t ws_size,
                              hipStream_t stream) {
  const int* idx = (const int*)d_in[0];
  const float* emb = (const float*)d_in[1];
  const float* W_ih = (const float*)d_in[2];
  const float* W_hh = (const float*)d_in[3];
  const float* b_ih = (const float*)d_in[4];
  const float* b_hh = (const float*)d_in[5];
  const float* W_out = (const float*)d_in[6];
  const float* b_out = (const float*)d_in[7];
  const float* h0 = (const float*)d_in[8];
  const float* c0 = (const float*)d_in[9];

  char* ws = (char*)d_ws;
  bf16_t* W_ih_bf = (bf16_t*)ws;            ws += 4096L * 512 * 2;
  bf16_t* W_hh_bf = (bf16_t*)ws;            ws += 4096L * 1024 * 2;
  bf16_t* W_out_bf = (bf16_t*)ws;           ws += 32000L * 1024 * 2;
  bf16_t* x_bf = (bf16_t*)ws;               ws += 4096L * 512 * 2;
  bf16_t* gates_x = (bf16_t*)ws;            ws += 4096L * 4096 * 2;
  bf16_t* h_all = (bf16_t*)ws;              ws += 4096L * 1024 * 2;
  bf16_t* h0_bf = (bf16_t*)ws;              ws += 32L * 1024 * 2;
  float* bc = (float*)ws;                   ws += 4096L * 4;
  float* rowS = (float*)ws;                 ws += 4096L * 4;
  float* tgt_logit = (float*)ws;            ws += 4096L * 4;
  int* tgt = (int*)ws;                      ws += 4096L * 4;
  unsigned* bar = (unsigned*)ws;            ws += 1024L * 4;

  k_prep<<<4096, 256, 0, stream>>>(idx, emb, W_ih, W_hh, b_ih, b_hh, W_out, h0,
                                   W_ih_bf, W_hh_bf, W_out_bf, x_bf, h_all, h0_bf,
                                   bc, rowS, tgt, bar);

  k_gemm1<<<dim3(64, 32), 256, 0, stream>>>(x_bf, W_ih_bf, bc, gates_x);

  {
    void* args[] = {(void*)&gates_x, (void*)&W_hh_bf, (void*)&h0_bf, (void*)&h_all,
                    (void*)&c0, (void*)&bar};
    hipLaunchCooperativeKernel((void*)k_rec9, dim3(NBLK), dim3(512), args, 0, stream);
  }

  k_gemm2<<<dim3(32, 250), 256, 0, stream>>>(h_all, W_out_bf, b_out, rowS);

  k_tgt<<<1016, 256, 0, stream>>>(h_all, W_out_bf, b_out, tgt, tgt_logit);

  k_loss<<<1, 256, 0, stream>>>(rowS, tgt_logit, tgt, (float*)d_out);
}

// Round 7
// 1243.382 us; speedup vs baseline: 1.1833x; 1.0145x over previous
//
#include <hip/hip_runtime.h>
#include <hip/hip_bf16.h>
#include <hip/hip_cooperative_groups.h>
#include <math.h>

namespace cg = cooperative_groups;

typedef __bf16 bf16_t;
typedef bf16_t bf16x8 __attribute__((ext_vector_type(8)));
typedef float f32x4 __attribute__((ext_vector_type(4)));
typedef unsigned u32x2 __attribute__((ext_vector_type(2)));
typedef unsigned u32x4 __attribute__((ext_vector_type(4)));

#define T_SEQ 128
#define NB 32
#define NV 32000
#define NE 512
#define NH 1024
#define G4 4096          // 4*NH
#define MROWS 4064       // 127*32
#define MPAD 4096

#define NBLK 256
#define SENT 0xFFFFFFFFu  // two bf16 NaNs; h = sig*tanh is always finite

// async global->LDS, 16B per lane, wave-uniform LDS base
__device__ __forceinline__ void g2lds16(const bf16_t* g, bf16_t* l) {
  __builtin_amdgcn_global_load_lds((const __attribute__((address_space(1))) void*)g,
                                   (__attribute__((address_space(3))) void*)l, 16, 0, 0);
}

__device__ __forceinline__ unsigned short bf16bits(float x) {
  bf16_t b = (bf16_t)x;
  return __builtin_bit_cast(unsigned short, b);
}

__device__ __forceinline__ void cvt4(const float* __restrict__ s,
                                     bf16_t* __restrict__ d, long j) {
  float4 v = *(const float4*)(s + j * 4);
  uint2 o;
  o.x = (unsigned)bf16bits(v.x) | ((unsigned)bf16bits(v.y) << 16);
  o.y = (unsigned)bf16bits(v.z) | ((unsigned)bf16bits(v.w) << 16);
  *(uint2*)(d + j * 4) = o;
}

// ---------------- prep v2: vectorized casts/gather + h_all sentinel init ----------------
__global__ void k_prep(const int* __restrict__ idx, const float* __restrict__ emb,
                       const float* __restrict__ W_ih, const float* __restrict__ W_hh,
                       const float* __restrict__ b_ih, const float* __restrict__ b_hh,
                       const float* __restrict__ W_out, const float* __restrict__ h0,
                       bf16_t* __restrict__ W_ih_bf, bf16_t* __restrict__ W_hh_bf,
                       bf16_t* __restrict__ W_out_bf, bf16_t* __restrict__ x_bf,
                       bf16_t* __restrict__ h_all, bf16_t* __restrict__ h0_bf,
                       float* __restrict__ bc, float* __restrict__ rowS,
                       int* __restrict__ tgt, unsigned* __restrict__ bar) {
  const long n4_Wih = 4096L * 512 / 4;     // 524288 float4
  const long n4_Whh = 4096L * 1024 / 4;    // 1048576
  const long n4_Wout = 32000L * 1024 / 4;  // 8192000
  const long n4_X = 4096L * 512 / 4;       // 524288
  const long n4_H0 = 32L * 1024 / 4;       // 8192
  const long n4_Hall = 4096L * 1024 / 8;   // 524288 uint4 over all of h_all
  const long nSentinel = 4064L * 128;      // 520192 uint4 = rows 0..4063
  const long nScal = 3 * 4096L + 1024;
  const long NTOT = n4_Wih + n4_Whh + n4_Wout + n4_X + n4_H0 + n4_Hall + nScal;
  long stride = (long)gridDim.x * blockDim.x;
  for (long i = (long)blockIdx.x * blockDim.x + threadIdx.x; i < NTOT; i += stride) {
    long j = i;
    if (j < n4_Wih) { cvt4(W_ih, W_ih_bf, j); continue; }
    j -= n4_Wih;
    if (j < n4_Whh) { cvt4(W_hh, W_hh_bf, j); continue; }
    j -= n4_Whh;
    if (j < n4_Wout) { cvt4(W_out, W_out_bf, j); continue; }
    j -= n4_Wout;
    if (j < n4_X) {
      long m = j >> 7; int e4 = (int)(j & 127);
      uint2 o; o.x = 0u; o.y = 0u;
      if (m < MROWS) {
        float4 v = *(const float4*)(emb + (long)idx[m] * NE + e4 * 4);
        v.x = fmaxf(v.x, 0.f); v.y = fmaxf(v.y, 0.f);
        v.z = fmaxf(v.z, 0.f); v.w = fmaxf(v.w, 0.f);
        o.x = (unsigned)bf16bits(v.x) | ((unsigned)bf16bits(v.y) << 16);
        o.y = (unsigned)bf16bits(v.z) | ((unsigned)bf16bits(v.w) << 16);
      }
      *(uint2*)(x_bf + m * 512 + e4 * 4) = o;
      continue;
    }
    j -= n4_X;
    if (j < n4_H0) { cvt4(h0, h0_bf, j); continue; }
    j -= n4_H0;
    if (j < n4_Hall) {
      // rows 0..4063: sentinel (never a valid packed h pair); pad rows: zero
      unsigned v = (j < nSentinel) ? SENT : 0u;
      uint4 s; s.x = v; s.y = v; s.z = v; s.w = v;
      ((uint4*)h_all)[j] = s;
      continue;
    }
    j -= n4_Hall;
    if (j < 4096) { bc[j] = b_ih[j] + b_hh[j]; continue; }
    j -= 4096;
    if (j < 4096) { rowS[j] = 0.f; continue; }
    j -= 4096;
    if (j < 4096) { tgt[j] = (j < MROWS) ? idx[j + NB] : 0; continue; }
    j -= 4096;
    { bar[j] = 0u; continue; }
  }
}

// ---------------- GEMM1: gates_x = x @ W_ih^T + (b_ih+b_hh), bf16 out ----------------
__global__ __launch_bounds__(256) void k_gemm1(const bf16_t* __restrict__ A,
                                               const bf16_t* __restrict__ B,
                                               const float* __restrict__ bc,
                                               bf16_t* __restrict__ C) {
  const int K = 512;
  int tid = threadIdx.x, wid = tid >> 6, lane = tid & 63;
  int wm = wid & 1, wn = wid >> 1;
  int quad = lane >> 4, l15 = lane & 15;
  int mBase = blockIdx.x * 64, nBase = blockIdx.y * 128;

  const bf16x8* pa0 = (const bf16x8*)(A + (long)(mBase + wm * 32 + l15) * K + quad * 8);
  const bf16x8* pa1 = (const bf16x8*)(A + (long)(mBase + wm * 32 + 16 + l15) * K + quad * 8);
  const bf16x8* pb[4];
#pragma unroll
  for (int j = 0; j < 4; ++j)
    pb[j] = (const bf16x8*)(B + (long)(nBase + wn * 64 + j * 16 + l15) * K + quad * 8);

  f32x4 acc[2][4];
#pragma unroll
  for (int mi = 0; mi < 2; ++mi)
#pragma unroll
    for (int ni = 0; ni < 4; ++ni) acc[mi][ni] = (f32x4){0.f, 0.f, 0.f, 0.f};

  for (int kk = 0; kk < K / 32; ++kk) {
    bf16x8 a0 = pa0[kk * 4], a1 = pa1[kk * 4];
    bf16x8 b0 = pb[0][kk * 4], b1 = pb[1][kk * 4], b2 = pb[2][kk * 4], b3 = pb[3][kk * 4];
    acc[0][0] = __builtin_amdgcn_mfma_f32_16x16x32_bf16(a0, b0, acc[0][0], 0, 0, 0);
    acc[0][1] = __builtin_amdgcn_mfma_f32_16x16x32_bf16(a0, b1, acc[0][1], 0, 0, 0);
    acc[0][2] = __builtin_amdgcn_mfma_f32_16x16x32_bf16(a0, b2, acc[0][2], 0, 0, 0);
    acc[0][3] = __builtin_amdgcn_mfma_f32_16x16x32_bf16(a0, b3, acc[0][3], 0, 0, 0);
    acc[1][0] = __builtin_amdgcn_mfma_f32_16x16x32_bf16(a1, b0, acc[1][0], 0, 0, 0);
    acc[1][1] = __builtin_amdgcn_mfma_f32_16x16x32_bf16(a1, b1, acc[1][1], 0, 0, 0);
    acc[1][2] = __builtin_amdgcn_mfma_f32_16x16x32_bf16(a1, b2, acc[1][2], 0, 0, 0);
    acc[1][3] = __builtin_amdgcn_mfma_f32_16x16x32_bf16(a1, b3, acc[1][3], 0, 0, 0);
  }
#pragma unroll
  for (int ni = 0; ni < 4; ++ni) {
    int col = nBase + wn * 64 + ni * 16 + l15;
    float bcv = bc[col];
#pragma unroll
    for (int mi = 0; mi < 2; ++mi)
#pragma unroll
      for (int r = 0; r < 4; ++r) {
        int row = mBase + wm * 32 + mi * 16 + quad * 4 + r;
        C[(long)row * G4 + col] = (bf16_t)(acc[mi][ni][r] + bcv);
      }
  }
}

// ---------------- LSTM recurrence v9: sentinel-validated h, ack removed ----------------
__global__ __launch_bounds__(512) void k_rec9(const bf16_t* __restrict__ gates_x,
                                              const bf16_t* __restrict__ W_hh_bf,
                                              const bf16_t* __restrict__ h0_bf,
                                              bf16_t* __restrict__ h_all,
                                              const float* __restrict__ c0,
                                              unsigned* __restrict__ bar) {
  __shared__ __align__(16) float red[32 * 68];  // row stride 68 floats

  int bid = blockIdx.x;
  int mi = bid & 1;              // batch half
  int hb = bid >> 1;             // 0..127 within half
  int gbase = hb * 8;            // first hidden unit owned by this block
  int tid = threadIdx.x, wid = tid >> 6, lane = tid & 63;
  int cg = wid & 1, kh = wid >> 1;
  int quad = lane >> 4, l15 = lane & 15;

  unsigned* genp = bar + mi * 512 + 288;          // write-once/step, poll target
  unsigned* flagp = bar + mi * 512 + 320 + hb;    // this block's write-once flag
  const unsigned* fp2 = bar + mi * 512 + 320 + (lane << 1);  // aggregator view
  bool isagg = (bid < 2) && (wid == 7);

  int wrow = (cg ? 2048 : 0) + ((l15 & 8) ? 1024 : 0) + gbase + (l15 & 7);
  const bf16x8* pw = (const bf16x8*)(W_hh_bf + (long)wrow * NH + kh * 256 + quad * 8);
  bf16x8 wfrag[8];
#pragma unroll
  for (int kk = 0; kk < 8; ++kk) wfrag[kk] = pw[kk * 4];  // resident in VGPRs

  // pointwise: threads 0..63 (wave 0): b = tid>>2, unit pair = (tid&3)*2
  int pb = tid >> 2, pu2 = (tid & 3) * 2;
  int u0 = gbase + pu2;
  int bglob = mi * 16 + pb;
  float cst0 = 0.f, cst1 = 0.f;
  if (tid < 64) {
    cst0 = c0[(long)bglob * NH + u0];
    cst1 = c0[(long)bglob * NH + u0 + 1];
  }
  unsigned* h32 = (unsigned*)h_all;

  for (int t = 0; t < T_SEQ - 1; ++t) {
    // prefetch gates_x pairs (independent of h_prev; overlaps gen wait)
    unsigned gxi2 = 0, gxf2 = 0, gxg2 = 0, gxo2 = 0;
    if (tid < 64) {
      const unsigned* gp = (const unsigned*)(gates_x + (long)(t * NB + bglob) * G4);
      int q = u0 >> 1;
      gxi2 = gp[q]; gxf2 = gp[512 + q]; gxg2 = gp[1024 + q]; gxo2 = gp[1536 + q];
    }

    if (t > 0) {
      // per-half aggregator: wave 7 of blocks 0/1 polls all 128 write-once
      // flags (one coalesced dwordx2/lane) and publishes gen with ONE store
      if (isagg) {
        unsigned need = (unsigned)t;
        while (1) {
          u32x2 fv;
          asm volatile("global_load_dwordx2 %0, %1, off sc0 sc1\n\t"
                       "s_waitcnt vmcnt(0)"
                       : "=&v"(fv) : "v"(fp2) : "memory");
          if (__all((fv.x >= need) & (fv.y >= need))) break;
          __builtin_amdgcn_s_sleep(1);
        }
        if (lane == 0)
          __hip_atomic_store(genp, (unsigned)t, __ATOMIC_RELAXED,
                             __HIP_MEMORY_SCOPE_AGENT);
      }
      // consumer detect: thread0 sleep-paced poll on write-once gen
      if (tid == 0) {
        unsigned need = (unsigned)t;
        while (__hip_atomic_load(genp, __ATOMIC_RELAXED,
                                 __HIP_MEMORY_SCOPE_AGENT) < need)
          __builtin_amdgcn_s_sleep(1);
      }
    }
    __syncthreads();  // barrier1: release block; also covers red anti-dep
    asm volatile("" ::: "memory");

    bf16x8 hfr[8];
    if (t == 0) {
      const bf16x8* pa0 =
          (const bf16x8*)(h0_bf + (long)(mi * 16 + l15) * NH + kh * 256 + quad * 8);
#pragma unroll
      for (int kk = 0; kk < 8; ++kk) hfr[kk] = pa0[kk * 4];
    } else {
      const bf16_t* hb8 = h_all + (long)(t - 1) * NB * NH +
                          (long)(mi * 16 + l15) * NH + kh * 256 + quad * 8;
      const bf16x8* pa = (const bf16x8*)hb8;
#pragma unroll
      for (int kk = 0; kk < 8; ++kk) hfr[kk] = pa[kk * 4];  // plain (L2-shared)
      unsigned bad = 0;
#pragma unroll
      for (int kk = 0; kk < 8; ++kk) {
        u32x4 w = __builtin_bit_cast(u32x4, hfr[kk]);
        bad |= (unsigned)(w.x == SENT) | (unsigned)(w.y == SENT) |
               (unsigned)(w.z == SENT) | (unsigned)(w.w == SENT);
      }
      while (!__all(bad == 0)) {  // rare: data still in flight — coherent retry
        __builtin_amdgcn_s_sleep(1);
        u32x4 hw[8];
#pragma unroll
        for (int kk = 0; kk < 8; ++kk)
          asm volatile("global_load_dwordx4 %0, %1, off sc0 sc1"
                       : "=&v"(hw[kk]) : "v"(hb8 + kk * 32) : "memory");
        asm volatile("s_waitcnt vmcnt(0)" ::: "memory");
        bad = 0;
#pragma unroll
        for (int kk = 0; kk < 8; ++kk) {
          bad |= (unsigned)(hw[kk].x == SENT) | (unsigned)(hw[kk].y == SENT) |
                 (unsigned)(hw[kk].z == SENT) | (unsigned)(hw[kk].w == SENT);
          hfr[kk] = __builtin_bit_cast(bf16x8, hw[kk]);
        }
      }
    }

    f32x4 acc = (f32x4){0.f, 0.f, 0.f, 0.f};
#pragma unroll
    for (int kk = 0; kk < 8; ++kk)
      acc = __builtin_amdgcn_mfma_f32_16x16x32_bf16(hfr[kk], wfrag[kk], acc, 0, 0, 0);
#pragma unroll
    for (int r = 0; r < 4; ++r) {
      int row = (cg << 4) + (quad << 2) + r;
      red[row * 68 + (l15 << 2) + kh] = acc[r];
    }
    __syncthreads();  // barrier2: red ready

    if (tid < 64) {
      const float* rc = red;
      float hv[2];
#pragma unroll
      for (int d = 0; d < 2; ++d) {
        int q = pu2 + d;
        float4 vi = *(const float4*)(rc + pb * 68 + (q << 2));
        float4 vf = *(const float4*)(rc + pb * 68 + ((8 + q) << 2));
        float4 vg = *(const float4*)(rc + (16 + pb) * 68 + (q << 2));
        float4 vo = *(const float4*)(rc + (16 + pb) * 68 + ((8 + q) << 2));
        unsigned bi = d ? (gxi2 & 0xffff0000u) : (gxi2 << 16);
        unsigned bff = d ? (gxf2 & 0xffff0000u) : (gxf2 << 16);
        unsigned bg = d ? (gxg2 & 0xffff0000u) : (gxg2 << 16);
        unsigned bo = d ? (gxo2 & 0xffff0000u) : (gxo2 << 16);
        float iv = vi.x + vi.y + vi.z + vi.w + __builtin_bit_cast(float, bi);
        float fv = vf.x + vf.y + vf.z + vf.w + __builtin_bit_cast(float, bff);
        float gv = vg.x + vg.y + vg.z + vg.w + __builtin_bit_cast(float, bg);
        float ov = vo.x + vo.y + vo.z + vo.w + __builtin_bit_cast(float, bo);
        float si = 1.f / (1.f + __expf(-iv));
        float sf = 1.f / (1.f + __expf(-fv));
        float so = 1.f / (1.f + __expf(-ov));
        float tg = 1.f - 2.f / (__expf(2.f * gv) + 1.f);
        float& cs = d ? cst1 : cst0;
        cs = sf * cs + si * tg;
        float th = 1.f - 2.f / (__expf(2.f * cs) + 1.f);
        hv[d] = so * th;
      }
      unsigned pack = (unsigned)bf16bits(hv[0]) | ((unsigned)bf16bits(hv[1]) << 16);
      // agent-scope write-through store: visible at LLC, no L2 dirty line
      __hip_atomic_store(&h32[(long)(t * NB + bglob) * 512 + (u0 >> 1)], pack,
                         __ATOMIC_RELAXED, __HIP_MEMORY_SCOPE_AGENT);
      // flag immediately — NO store-ack. Ordering vs h is irrelevant:
      // consumers sentinel-validate the data itself.
      if (t < T_SEQ - 2 && tid == 0)
        __hip_atomic_store(flagp, (unsigned)(t + 1), __ATOMIC_RELAXED,
                           __HIP_MEMORY_SCOPE_AGENT);
    }
  }
}

// ---------------- GEMM2 v4: 256x256 tile, counted-vmcnt pipeline ----------------
// v3 minus the LDS overage: SA+SB = exactly 128 KiB (the verified template
// footprint); epilogue reverts to direct global atomics (no rsum LDS).
// 512 threads = 8 waves (2M x 4N); per-wave output 128x64; BK=64, 16 K-tiles.
// Staging via global_load_lds with PRE-SWIZZLED source (rule #21): linear LDS
// dest + col ^= ((row>>2)&1)<<4 on source AND read (st_16x32 involution).
// Per K-tile: reads ks0 -> 32 MFMA -> reads ks1 -> lgkmcnt(0) -> s_barrier
// (all reads of buf[cur] retired) -> STAGE(buf[cur], kt+2) -> setprio(1) ->
// 32 MFMA (overlaps staging) -> setprio(0) -> vmcnt(8) (tile kt+1 landed,
// kt+2's 8 loads stay in flight) -> s_barrier. Raw s_barrier avoids
// __syncthreads' implicit vmcnt(0) drain (the documented m97 ~20% stall).
__global__ __launch_bounds__(512, 2) void k_gemm2(const bf16_t* __restrict__ A,
                                                  const bf16_t* __restrict__ B,
                                                  const float* __restrict__ b_out,
                                                  float* __restrict__ rowS) {
  __shared__ bf16_t SA[2][256 * 64];
  __shared__ bf16_t SB[2][256 * 64];
  const int K = 1024;
  const int NT = 16;  // K / 64
  int tid = threadIdx.x, wid = tid >> 6, lane = tid & 63;
  int wm = wid >> 2, wn = wid & 3;
  int quad = lane >> 4, l15 = lane & 15;
  int mBase = blockIdx.x * 256, nBase = blockIdx.y * 256;

  // stage one 256x64 K-tile of A and B into buf (8 x global_load_lds / thread)
#define STAGE2(buf, kt)                                                       \
  {                                                                           \
    _Pragma("unroll") for (int r = 0; r < 4; ++r) {                           \
      int o16 = r * 512 + tid;                                                \
      int row = o16 >> 3;                                                     \
      int col = ((o16 & 7) << 3) ^ (((row >> 2) & 1) << 4);                   \
      g2lds16(A + (size_t)(mBase + row) * K + (kt) * 64 + col,                \
              &SA[buf][(r * 512 + wid * 64) * 8]);                            \
    }                                                                         \
    _Pragma("unroll") for (int r = 0; r < 4; ++r) {                           \
      int o16 = r * 512 + tid;                                                \
      int row = o16 >> 3;                                                     \
      int col = ((o16 & 7) << 3) ^ (((row >> 2) & 1) << 4);                   \
      g2lds16(B + (size_t)(nBase + row) * K + (kt) * 64 + col,                \
              &SB[buf][(r * 512 + wid * 64) * 8]);                            \
    }                                                                         \
  }

  f32x4 acc[8][4];
#pragma unroll
  for (int i = 0; i < 8; ++i)
#pragma unroll
    for (int j = 0; j < 4; ++j) acc[i][j] = (f32x4){0.f, 0.f, 0.f, 0.f};

  STAGE2(0, 0);
  STAGE2(1, 1);
  asm volatile("s_waitcnt vmcnt(8)" ::: "memory");  // tile 0 landed; tile 1 in flight
  __builtin_amdgcn_s_barrier();

  for (int kt = 0; kt < NT; ++kt) {
    int cur = kt & 1;
    const bf16_t* sa = SA[cur];
    const bf16_t* sb = SB[cur];
    bf16x8 af[8], bfr[4];
    // ---- ks = 0 ----
#pragma unroll
    for (int mf = 0; mf < 8; ++mf) {
      int ra = wm * 128 + mf * 16 + l15;
      int c = (quad * 8) ^ (((ra >> 2) & 1) << 4);
      af[mf] = *(const bf16x8*)(sa + ra * 64 + c);
    }
#pragma unroll
    for (int nf = 0; nf < 4; ++nf) {
      int rb = wn * 64 + nf * 16 + l15;
      int c = (quad * 8) ^ (((rb >> 2) & 1) << 4);
      bfr[nf] = *(const bf16x8*)(sb + rb * 64 + c);
    }
#pragma unroll
    for (int mf = 0; mf < 8; ++mf)
#pragma unroll
      for (int nf = 0; nf < 4; ++nf)
        acc[mf][nf] =
            __builtin_amdgcn_mfma_f32_16x16x32_bf16(af[mf], bfr[nf], acc[mf][nf], 0, 0, 0);
    // ---- ks = 1 reads (buf[cur] read-only until the barrier below) ----
#pragma unroll
    for (int mf = 0; mf < 8; ++mf) {
      int ra = wm * 128 + mf * 16 + l15;
      int c = (32 + quad * 8) ^ (((ra >> 2) & 1) << 4);
      af[mf] = *(const bf16x8*)(sa + ra * 64 + c);
    }
#pragma unroll
    for (int nf = 0; nf < 4; ++nf) {
      int rb = wn * 64 + nf * 16 + l15;
      int c = (32 + quad * 8) ^ (((rb >> 2) & 1) << 4);
      bfr[nf] = *(const bf16x8*)(sb + rb * 64 + c);
    }
    asm volatile("s_waitcnt lgkmcnt(0)" ::: "memory");  // my LDS reads executed
    __builtin_amdgcn_sched_barrier(0);
    __builtin_amdgcn_s_barrier();  // ALL waves done reading buf[cur] -> overwrite ok
    if (kt + 2 < NT) STAGE2(cur, kt + 2);
    __builtin_amdgcn_s_setprio(1);
#pragma unroll
    for (int mf = 0; mf < 8; ++mf)
#pragma unroll
      for (int nf = 0; nf < 4; ++nf)
        acc[mf][nf] =
            __builtin_amdgcn_mfma_f32_16x16x32_bf16(af[mf], bfr[nf], acc[mf][nf], 0, 0, 0);
    __builtin_amdgcn_s_setprio(0);
    if (kt + 2 < NT) {
      asm volatile("s_waitcnt vmcnt(8)" ::: "memory");  // tile kt+1 landed
    } else {
      asm volatile("s_waitcnt vmcnt(0)" ::: "memory");  // epilogue drain
    }
    __builtin_amdgcn_s_barrier();
  }
#undef STAGE2

  // ---- epilogue: exp-rowsum, direct global atomics (proven pattern) ----
#pragma unroll
  for (int mf = 0; mf < 8; ++mf) {
    float rs[4] = {0.f, 0.f, 0.f, 0.f};
#pragma unroll
    for (int nf = 0; nf < 4; ++nf) {
      float bb = b_out[nBase + wn * 64 + nf * 16 + l15];
#pragma unroll
      for (int r = 0; r < 4; ++r) rs[r] += __expf(acc[mf][nf][r] + bb);
    }
#pragma unroll
    for (int r = 0; r < 4; ++r) {
#pragma unroll
      for (int s = 1; s < 16; s <<= 1) rs[r] += __shfl_xor(rs[r], s);
      if (l15 == 0) {
        int row = mBase + wm * 128 + mf * 16 + quad * 4 + r;
        if (row < MROWS) atomicAdd(&rowS[row], rs[r]);
      }
    }
  }
}

// ---------------- target logits ----------------
__global__ __launch_bounds__(256) void k_tgt(const bf16_t* __restrict__ h_all,
                                             const bf16_t* __restrict__ W_out_bf,
                                             const float* __restrict__ b_out,
                                             const int* __restrict__ tgt,
                                             float* __restrict__ tgt_logit) {
  int gw = (int)((blockIdx.x * blockDim.x + threadIdx.x) >> 6);
  int lane = threadIdx.x & 63;
  if (gw >= MROWS) return;
  int v = tgt[gw];
  const bf16x8* ph = (const bf16x8*)(h_all + (long)gw * NH + lane * 16);
  const bf16x8* pw = (const bf16x8*)(W_out_bf + (long)v * NH + lane * 16);
  float acc = 0.f;
#pragma unroll
  for (int j = 0; j < 2; ++j) {
    bf16x8 h8 = ph[j], w8 = pw[j];
#pragma unroll
    for (int q = 0; q < 8; ++q) acc += (float)h8[q] * (float)w8[q];
  }
#pragma unroll
  for (int s = 1; s < 64; s <<= 1) acc += __shfl_xor(acc, s);
  if (lane == 0) tgt_logit[gw] = acc + b_out[v];
}

// ---------------- final loss reduction ----------------
__global__ __launch_bounds__(256) void k_loss(const float* __restrict__ rowS,
                                              const float* __restrict__ tl,
                                              const int* __restrict__ tgt,
                                              float* __restrict__ out) {
  __shared__ float sm[256];
  float s = 0.f;
  for (int i = threadIdx.x; i < MROWS; i += 256)
    if (tgt[i] != 0) s += logf(rowS[i]) - tl[i];
  sm[threadIdx.x] = s;
  __syncthreads();
  for (int off = 128; off > 0; off >>= 1) {
    if (threadIdx.x < off) sm[threadIdx.x] += sm[threadIdx.x + off];
    __syncthreads();
  }
  if (threadIdx.x == 0) out[0] = sm[0];
}

extern "C" void kernel_launch(void* const* d_in, const int* in_sizes, int n_in,
                              void* d_out, int out_size, void* d_ws, size_t ws_size,
                              hipStream_t stream) {
  const int* idx = (const int*)d_in[0];
  const float* emb = (const float*)d_in[1];
  const float* W_ih = (const float*)d_in[2];
  const float* W_hh = (const float*)d_in[3];
  const float* b_ih = (const float*)d_in[4];
  const float* b_hh = (const float*)d_in[5];
  const float* W_out = (const float*)d_in[6];
  const float* b_out = (const float*)d_in[7];
  const float* h0 = (const float*)d_in[8];
  const float* c0 = (const float*)d_in[9];

  char* ws = (char*)d_ws;
  bf16_t* W_ih_bf = (bf16_t*)ws;            ws += 4096L * 512 * 2;
  bf16_t* W_hh_bf = (bf16_t*)ws;            ws += 4096L * 1024 * 2;
  bf16_t* W_out_bf = (bf16_t*)ws;           ws += 32000L * 1024 * 2;
  bf16_t* x_bf = (bf16_t*)ws;               ws += 4096L * 512 * 2;
  bf16_t* gates_x = (bf16_t*)ws;            ws += 4096L * 4096 * 2;
  bf16_t* h_all = (bf16_t*)ws;              ws += 4096L * 1024 * 2;
  bf16_t* h0_bf = (bf16_t*)ws;              ws += 32L * 1024 * 2;
  float* bc = (float*)ws;                   ws += 4096L * 4;
  float* rowS = (float*)ws;                 ws += 4096L * 4;
  float* tgt_logit = (float*)ws;            ws += 4096L * 4;
  int* tgt = (int*)ws;                      ws += 4096L * 4;
  unsigned* bar = (unsigned*)ws;            ws += 1024L * 4;

  k_prep<<<4096, 256, 0, stream>>>(idx, emb, W_ih, W_hh, b_ih, b_hh, W_out, h0,
                                   W_ih_bf, W_hh_bf, W_out_bf, x_bf, h_all, h0_bf,
                                   bc, rowS, tgt, bar);

  k_gemm1<<<dim3(64, 32), 256, 0, stream>>>(x_bf, W_ih_bf, bc, gates_x);

  {
    void* args[] = {(void*)&gates_x, (void*)&W_hh_bf, (void*)&h0_bf, (void*)&h_all,
                    (void*)&c0, (void*)&bar};
    hipLaunchCooperativeKernel((void*)k_rec9, dim3(NBLK), dim3(512), args, 0, stream);
  }

  k_gemm2<<<dim3(16, 125), 512, 0, stream>>>(h_all, W_out_bf, b_out, rowS);

  k_tgt<<<1016, 256, 0, stream>>>(h_all, W_out_bf, b_out, tgt, tgt_logit);

  k_loss<<<1, 256, 0, stream>>>(rowS, tgt_logit, tgt, (float*)d_out);
}